// Round 6
// baseline (387.958 us; speedup 1.0000x reference)
//
#include <hip/hip_runtime.h>
#include <stdint.h>
#include <math.h>

#define HH 512
#define WW 512
#define BB 32
#define CC 3
#define HWSZ (HH*WW)            // 262144
#define CHW (CC*HWSZ)           // 786432
#define NIMG (BB*CHW)           // 25165824
#define NMSK (BB*HWSZ)          // 8388608

// ---------------- Threefry-2x32 core ----------------
__host__ __device__ inline uint32_t rotl32(uint32_t x, uint32_t r){ return (x<<r)|(x>>(32u-r)); }

__host__ __device__ inline void tf2x32(uint32_t k0, uint32_t k1, uint32_t x0, uint32_t x1,
                                       uint32_t& o0, uint32_t& o1){
  uint32_t kx = k0 ^ k1 ^ 0x1BD11BDAu;
  uint32_t ks[3] = {k0, k1, kx};
  const uint32_t R[2][4] = {{13u,15u,26u,6u},{17u,29u,16u,24u}};
  x0 += ks[0]; x1 += ks[1];
  #pragma unroll
  for (int i = 0; i < 5; ++i){
    #pragma unroll
    for (int j = 0; j < 4; ++j){
      x0 += x1; x1 = rotl32(x1, R[i & 1][j]); x1 ^= x0;
    }
    x0 += ks[(i+1)%3];
    x1 += ks[(i+2)%3] + (uint32_t)(i+1);
  }
  o0 = x0; o1 = x1;
}

__host__ __device__ inline float bits_to_u01(uint32_t b){
  uint32_t fb = (b >> 9) | 0x3f800000u;
  float f;
#ifdef __HIP_DEVICE_COMPILE__
  f = __uint_as_float(fb);
#else
  union { uint32_t u; float f; } cv; cv.u = fb; f = cv.f;
#endif
  return f - 1.0f;
}

// XLA f32 ErfInv polynomial
__host__ __device__ inline float erfinv_f32(float x){
  float w = -log1pf(-x*x);
  float p;
  if (w < 5.0f){
    w -= 2.5f;
    p = 2.81022636e-08f;
    p = fmaf(p, w, 3.43273939e-07f);
    p = fmaf(p, w, -3.5233877e-06f);
    p = fmaf(p, w, -4.39150654e-06f);
    p = fmaf(p, w, 0.00021858087f);
    p = fmaf(p, w, -0.00125372503f);
    p = fmaf(p, w, -0.00417768164f);
    p = fmaf(p, w, 0.246640727f);
    p = fmaf(p, w, 1.50140941f);
  } else {
    w = sqrtf(w) - 3.0f;
    p = -0.000200214257f;
    p = fmaf(p, w, 0.000100950558f);
    p = fmaf(p, w, 0.00134934322f);
    p = fmaf(p, w, -0.00367342844f);
    p = fmaf(p, w, 0.00573950773f);
    p = fmaf(p, w, -0.0076224613f);
    p = fmaf(p, w, 0.00943887047f);
    p = fmaf(p, w, 1.00167406f);
    p = fmaf(p, w, 2.83297682f);
  }
  return p * x;
}

#define NRM_LO (-0.9999999403953552f)   /* nextafterf(-1,0) */
#define SQRT2F 1.41421356237309504880f

__host__ __device__ inline float normal_from_bits(uint32_t b){
  float f = bits_to_u01(b);
  float val = f * 2.0f + NRM_LO;    // (hi-lo) rounds to exactly 2.0f
  val = fmaxf(NRM_LO, val);
  return SQRT2F * erfinv_f32(val);
}

// ---------------- host-side jax.random (PARTITIONABLE threefry) ----------------
struct Key { uint32_t a, b; };

static Key foldSplit(Key k, uint32_t j){
  Key r; tf2x32(k.a, k.b, 0u, j, r.a, r.b); return r;
}

static uint32_t bits32(Key k, uint32_t i){
  uint32_t o0, o1; tf2x32(k.a, k.b, 0u, i, o0, o1); return o0 ^ o1;
}

static float unif_scalar(Key k){ return bits_to_u01(bits32(k, 0u)); }
static float normal_scalar(Key k){ return normal_from_bits(bits32(k, 0u)); }

static uint32_t gate_mask(Key kg){
  Key k1 = foldSplit(kg, 0u);
  Key k2 = foldSplit(kg, 1u);
  Key kl = foldSplit(k1, 1u);           // lower-bits key (second subkey)
  float u = bits_to_u01(bits32(k2, 0u));
  uint32_t m = 0;
  for (uint32_t i = 0; i < 32; ++i){
    float bern = (float)(bits32(kl, i) & 1u);
    if (bern * 0.8f > u) m |= (1u << i);
  }
  return m;
}

// ---------------- params ----------------
struct AugParams {
  uint32_t mFlip, mRot90, mTrans, mRot, mHue, mBri, mCon, mSat, mSharp, mNoise;
  float t, rotC, rotS, hShift, bri, con, sat, shp;
  uint32_t nk0, nk1;
};

// ---------------- device helpers ----------------
__device__ inline float clip01(float v){ return fminf(fmaxf(v, 0.0f), 1.0f); }

__device__ inline void permIdx(int y, int x, bool r9, bool fl, int& py, int& px){
  if (r9){ py = x; px = 511 - y; } else { py = y; px = x; }
  if (fl) px = 511 - px;
}

__device__ inline float tapP(const float* __restrict__ src, int y, int x, bool r9, bool fl){
  if ((unsigned)x >= 512u || (unsigned)y >= 512u) return 0.0f;
  int py, px; permIdx(y, x, r9, fl, py, px);
  return (src[py*512 + px] + 1.0f) * 0.5f;
}

// stage-1 (translate ∘ perm ∘ normalize), (ty,tx) in [0,512)
__device__ inline void stage1RGB(const float* __restrict__ base, int ty, int tx,
                                 bool r9, bool fl, bool tr, float t, float out[3]){
  if (!tr){
    #pragma unroll
    for (int c = 0; c < 3; ++c) out[c] = tapP(base + c*HWSZ, ty, tx, r9, fl);
    return;
  }
  float sx = (((float)tx - 255.5f) - t) + 255.5f;
  float sy = (((float)ty - 255.5f) - t) + 255.5f;
  float x0f = floorf(sx), y0f = floorf(sy);
  float wx = sx - x0f, wy = sy - y0f;
  int x0 = (int)x0f, y0 = (int)y0f;
  #pragma unroll
  for (int c = 0; c < 3; ++c){
    const float* s = base + c*HWSZ;
    float v00 = tapP(s, y0,   x0,   r9, fl);
    float v01 = tapP(s, y0,   x0+1, r9, fl);
    float v10 = tapP(s, y0+1, x0,   r9, fl);
    float v11 = tapP(s, y0+1, x0+1, r9, fl);
    float top = v00*(1.0f-wx) + v01*wx;
    float bot = v10*(1.0f-wx) + v11*wx;
    out[c] = top*(1.0f-wy) + bot*wy;
  }
}

__device__ inline void rotTap(const float* __restrict__ base, int ty, int tx,
                              bool r9, bool fl, bool tr, float t, float o[3]){
  if ((unsigned)tx < 512u && (unsigned)ty < 512u){
    stage1RGB(base, ty, tx, r9, fl, tr, t, o);
  } else {
    o[0] = o[1] = o[2] = 0.0f;
  }
}

// branchless (cndmask) HSV conversions — selection among identically-computed
// candidates, bit-exact vs. the if/else versions.
__device__ inline void rgb2hsv(float r, float g, float b, float& h, float& s, float& v){
  float maxc = fmaxf(fmaxf(r, g), b);
  float minc = fminf(fminf(r, g), b);
  float cr = maxc - minc;
  s = cr / ((maxc == 0.0f) ? 1.0f : maxc);
  float crd = (cr == 0.0f) ? 1.0f : cr;
  float rc = (maxc - r) / crd;
  float gc = (maxc - g) / crd;
  float bc = (maxc - b) / crd;
  float hh = (maxc == r) ? (bc - gc) : ((maxc == g) ? (2.0f + rc - bc) : (4.0f + gc - rc));
  float hd = hh / 6.0f;
  hd = hd - floorf(hd);
  h = (cr == 0.0f) ? 0.0f : hd;
  v = maxc;
}

__device__ inline void hsv2rgb(float h, float s, float v, float& r, float& g, float& b){
  float i = floorf(h * 6.0f);
  float f = h * 6.0f - i;
  float p = v * (1.0f - s);
  float q = v * (1.0f - f * s);
  float t = v * (1.0f - (1.0f - f) * s);
  int ii = ((int)i) % 6;
  r = (ii == 0 || ii == 5) ? v : (ii == 1) ? q : (ii == 4) ? t : p;
  g = (ii == 0) ? t : (ii <= 2) ? v : (ii == 3) ? q : p;
  b = (ii <= 1) ? p : (ii == 2) ? t : (ii <= 4) ? v : q;
}

// hue+brightness on a pixel already in stage-1 space
__device__ inline void applyHB(float v[3], bool hue, bool bri, const AugParams& P){
  if (hue){
    float r = clip01(v[0]), g = clip01(v[1]), bb = clip01(v[2]);
    float h, s, val;
    rgb2hsv(r, g, bb, h, s, val);
    h = h + P.hShift;
    h = h - floorf(h);
    hsv2rgb(h, s, val, v[0], v[1], v[2]);
  }
  if (bri){
    #pragma unroll
    for (int c = 0; c < 3; ++c) v[c] = clip01(v[c] * P.bri);
  }
}

// stage-2: perm+translate+rotate+hue+brightness, straight from input
__device__ inline void stage2RGB(const float* __restrict__ base, int yy, int xx,
                                 const AugParams& P, int b, float v[3]){
  bool fl  = (P.mFlip  >> b) & 1u;
  bool r9  = (P.mRot90 >> b) & 1u;
  bool tr  = (P.mTrans >> b) & 1u;
  bool rot = (P.mRot   >> b) & 1u;
  if (rot){
    float dx = (float)xx - 255.5f;
    float dy = (float)yy - 255.5f;
    float sx = (P.rotC*dx + P.rotS*dy) + 255.5f;
    float sy = (-P.rotS*dx + P.rotC*dy) + 255.5f;
    float x0f = floorf(sx), y0f = floorf(sy);
    float wx = sx - x0f, wy = sy - y0f;
    int x0 = (int)x0f, y0 = (int)y0f;
    float q00[3], q01[3], q10[3], q11[3];
    rotTap(base, y0,   x0,   r9, fl, tr, P.t, q00);
    rotTap(base, y0,   x0+1, r9, fl, tr, P.t, q01);
    rotTap(base, y0+1, x0,   r9, fl, tr, P.t, q10);
    rotTap(base, y0+1, x0+1, r9, fl, tr, P.t, q11);
    #pragma unroll
    for (int c = 0; c < 3; ++c){
      float top = q00[c]*(1.0f-wx) + q01[c]*wx;
      float bot = q10[c]*(1.0f-wx) + q11[c]*wx;
      v[c] = top*(1.0f-wy) + bot*wy;
    }
  } else {
    stage1RGB(base, yy, xx, r9, fl, tr, P.t, v);
  }
  applyHB(v, (P.mHue >> b) & 1u, (P.mBri >> b) & 1u, P);
}

// stage-2 reading materialized stage-1 buffer (rot batches): gather is row-local.
__device__ inline float s1at(const float* __restrict__ s, int y, int x){
  return ((unsigned)x < 512u && (unsigned)y < 512u) ? s[y*512 + x] : 0.0f;
}

__device__ inline void stage2S1(const float* __restrict__ s1b, int yy, int xx,
                                const AugParams& P, int b, float v[3]){
  bool rot = (P.mRot >> b) & 1u;
  bool hue = (P.mHue >> b) & 1u;
  bool bri = (P.mBri >> b) & 1u;
  if (rot){
    float dx = (float)xx - 255.5f;
    float dy = (float)yy - 255.5f;
    float sx = (P.rotC*dx + P.rotS*dy) + 255.5f;
    float sy = (-P.rotS*dx + P.rotC*dy) + 255.5f;
    float x0f = floorf(sx), y0f = floorf(sy);
    float wx = sx - x0f, wy = sy - y0f;
    int x0 = (int)x0f, y0 = (int)y0f;
    #pragma unroll
    for (int c = 0; c < 3; ++c){
      const float* s = s1b + c*HWSZ;
      float v00 = s1at(s, y0,   x0);
      float v01 = s1at(s, y0,   x0+1);
      float v10 = s1at(s, y0+1, x0);
      float v11 = s1at(s, y0+1, x0+1);
      float top = v00*(1.0f-wx) + v01*wx;
      float bot = v10*(1.0f-wx) + v11*wx;
      v[c] = top*(1.0f-wy) + bot*wy;
    }
  } else {
    #pragma unroll
    for (int c = 0; c < 3; ++c) v[c] = s1b[c*HWSZ + yy*512 + xx];
  }
  applyHB(v, hue, bri, P);
}

__device__ inline void procCS(float v[3], bool con, float cmul, float cadd, bool sat, float smul){
  if (con){
    #pragma unroll
    for (int c = 0; c < 3; ++c) v[c] = clip01(cmul * v[c] + cadd);
  }
  if (sat){
    float g = 0.2989f*v[0] + 0.587f*v[1] + 0.114f*v[2];
    float gadd = (1.0f - smul) * g;
    #pragma unroll
    for (int c = 0; c < 3; ++c) v[c] = clip01(smul * v[c] + gadd);
  }
}

// ---------------- kernels ----------------

// ===== FAST PATH =====

// K1: fused stage-1 image (z<32, ROT batches only materialize) + mask stage (z>=32).
// !rot && con image batches: read-only stage-2 mean accumulation (no S1 write).
// !rot && !con image batches: nothing.
__global__ __launch_bounds__(256) void kStage1M(const float* __restrict__ img,
                                                const float* __restrict__ msk,
                                                float* __restrict__ S1,
                                                float* __restrict__ M1,
                                                float* __restrict__ outMsk,
                                                float* __restrict__ meanAcc, AugParams P){
  __shared__ float ptile[3][33][33];
  __shared__ float wsum[4];
  int zz = blockIdx.z;
  int tx = threadIdx.x, ty = threadIdx.y;
  int tid = ty*32 + tx;
  int X0 = blockIdx.x*32, Y0 = blockIdx.y*32;

  if (zz >= BB){
    // ---------- mask stage ----------
    int b = zz - BB;
    bool fl  = (P.mFlip  >> b) & 1u;
    bool r9  = (P.mRot90 >> b) & 1u;
    bool rot = (P.mRot   >> b) & 1u;
    const float* src = msk + (size_t)b*HWSZ;
    float* dst = (rot ? M1 : outMsk) + (size_t)b*HWSZ;
    if (!r9){
      int row = tid >> 3, q = tid & 7;
      int y = Y0 + row, x4 = X0 + q*4;
      float4 u;
      if (!fl){
        u = *(const float4*)(src + y*512 + x4);
      } else {
        float4 w = *(const float4*)(src + y*512 + (508 - x4));
        u = make_float4(w.w, w.z, w.y, w.x);
      }
      *(float4*)(dst + y*512 + x4) = u;
    } else {
      float (*mtile)[33] = reinterpret_cast<float(*)[33]>(&ptile[0][0][0]);
      for (int idx = tid; idx < 32*32; idx += 256){
        int r = idx >> 5, q = idx & 31;
        int xx = X0 + r;                  // output col == src row
        int yy = Y0 + q;                  // output row -> src col
        int col = fl ? yy : (511 - yy);
        mtile[q][r] = src[xx*512 + col];
      }
      __syncthreads();
      #pragma unroll
      for (int k = 0; k < 4; ++k){
        int y = Y0 + ty + 8*k, x = X0 + tx;
        dst[y*512 + x] = mtile[ty + 8*k][tx];
      }
    }
    return;
  }

  // ---------- image ----------
  int b = zz;
  bool fl  = (P.mFlip  >> b) & 1u;
  bool r9  = (P.mRot90 >> b) & 1u;
  bool tr  = (P.mTrans >> b) & 1u;
  bool rot = (P.mRot   >> b) & 1u;
  bool con = (P.mCon   >> b) & 1u;
  const float* base = img + (size_t)b*CHW;
  float t = P.t;

  if (!rot){
    if (!con) return;
    // read-only stage-2 mean accumulation (no S1 materialization)
    float gsum = 0.0f;
    #pragma unroll
    for (int k = 0; k < 4; ++k){
      int y = Y0 + ty + 8*k, x = X0 + tx;
      float v[3];
      stage2RGB(base, y, x, P, b, v);   // rot=false internally
      gsum += 0.2989f*v[0] + 0.587f*v[1] + 0.114f*v[2];
    }
    #pragma unroll
    for (int off = 32; off > 0; off >>= 1) gsum += __shfl_down(gsum, off);
    int wid = tid >> 6, lid = tid & 63;
    if (lid == 0) wsum[wid] = gsum;
    __syncthreads();
    if (tid == 0) atomicAdd(&meanAcc[b], wsum[0] + wsum[1] + wsum[2] + wsum[3]);
    return;
  }

  // rot: materialize S1
  float* dstb = S1 + (size_t)b*CHW;
  if (!r9 && !tr){
    int row = tid >> 3, q = tid & 7;
    int y = Y0 + row, x4 = X0 + q*4;
    #pragma unroll
    for (int c = 0; c < 3; ++c){
      float4 u;
      if (!fl){
        u = *(const float4*)(base + c*HWSZ + y*512 + x4);
      } else {
        float4 w = *(const float4*)(base + c*HWSZ + y*512 + (508 - x4));
        u = make_float4(w.w, w.z, w.y, w.x);
      }
      u.x = (u.x + 1.0f)*0.5f; u.y = (u.y + 1.0f)*0.5f;
      u.z = (u.z + 1.0f)*0.5f; u.w = (u.w + 1.0f)*0.5f;
      *(float4*)(dstb + c*HWSZ + y*512 + x4) = u;
    }
  } else if (!r9){
    // translate-only
    #pragma unroll
    for (int k = 0; k < 4; ++k){
      int y = Y0 + ty + 8*k, x = X0 + tx;
      float v[3];
      stage1RGB(base, y, x, false, fl, true, t, v);
      #pragma unroll
      for (int c = 0; c < 3; ++c)
        dstb[(size_t)c*HWSZ + (size_t)y*512 + x] = v[c];
    }
  } else {
    // r9 (optionally + tr): staged LDS transpose, all channels, single barrier
    #pragma unroll
    for (int c = 0; c < 3; ++c){
      const float* src = base + c*HWSZ;
      for (int idx = tid; idx < 33*33; idx += 256){
        int r = idx / 33, q = idx - r*33;
        int xx = X0 - 1 + r;      // output col == src row
        int yy = Y0 - 1 + q;      // output row -> src col
        float val = 0.0f;
        if ((unsigned)yy < 512u && (unsigned)xx < 512u){
          int col = fl ? yy : (511 - yy);
          val = (src[xx*512 + col] + 1.0f) * 0.5f;
        }
        ptile[c][q][r] = val;     // transpose store
      }
    }
    __syncthreads();
    #pragma unroll
    for (int k = 0; k < 4; ++k){
      int y = Y0 + ty + 8*k, x = X0 + tx;
      float v[3];
      if (tr){
        float sx = (((float)x - 255.5f) - t) + 255.5f;
        float sy = (((float)y - 255.5f) - t) + 255.5f;
        float x0f = floorf(sx), y0f = floorf(sy);
        float wx = sx - x0f, wy = sy - y0f;
        int lx0 = (int)x0f - (X0 - 1);
        int ly0 = (int)y0f - (Y0 - 1);
        #pragma unroll
        for (int c = 0; c < 3; ++c){
          float v00 = ptile[c][ly0][lx0],   v01 = ptile[c][ly0][lx0+1];
          float v10 = ptile[c][ly0+1][lx0], v11 = ptile[c][ly0+1][lx0+1];
          float top = v00*(1.0f-wx) + v01*wx;
          float bot = v10*(1.0f-wx) + v11*wx;
          v[c] = top*(1.0f-wy) + bot*wy;
        }
      } else {
        #pragma unroll
        for (int c = 0; c < 3; ++c) v[c] = ptile[c][ty+8*k+1][tx+1];
      }
      #pragma unroll
      for (int c = 0; c < 3; ++c)
        dstb[(size_t)c*HWSZ + (size_t)y*512 + x] = v[c];
    }
  }
}

// K2: contrast mean for rot && con batches only (from S1, row-local gather).
__global__ __launch_bounds__(256) void kMean2(const float* __restrict__ S1,
                                              float* __restrict__ meanAcc, AugParams P){
  int b = blockIdx.z;
  if (!((P.mCon >> b) & 1u) || !((P.mRot >> b) & 1u)) return;
  int tid = threadIdx.x;                 // 256 threads, 1-D block
  const float* base = S1 + (size_t)b*CHW;
  int pbase = blockIdx.x * 4096;         // 64 blocks cover 262144 px
  float lsum = 0.0f;

  #pragma unroll 4
  for (int j = 0; j < 16; ++j){
    int px = pbase + j*256 + tid;
    int y = px >> 9, x = px & 511;
    float v[3];
    stage2S1(base, y, x, P, b, v);
    lsum += 0.2989f*v[0] + 0.587f*v[1] + 0.114f*v[2];
  }

  #pragma unroll
  for (int off = 32; off > 0; off >>= 1) lsum += __shfl_down(lsum, off);
  __shared__ float wsum[4];
  int wid = tid >> 6, lid = tid & 63;
  if (lid == 0) wsum[wid] = lsum;
  __syncthreads();
  if (tid == 0) atomicAdd(&meanAcc[b], wsum[0] + wsum[1] + wsum[2] + wsum[3]);
}

// K3: fused final image (z<32) + mask nearest-rotation (z>=32).
// rot batches read S1; !rot batches compute stage-1/2 on the fly from input.
__global__ __launch_bounds__(256) void kFinalM(const float* __restrict__ img,
                                               const float* __restrict__ S1,
                                               const float* __restrict__ M1,
                                               const float* __restrict__ meanAcc,
                                               float* __restrict__ out,
                                               float* __restrict__ outMsk, AugParams P){
  __shared__ float s2[34][34][3];
  int zz = blockIdx.z;
  int tx = threadIdx.x, ty = threadIdx.y;
  int tid = ty*32 + tx;
  int bx = blockIdx.x, by = blockIdx.y;

  if (zz >= BB){
    // ---------- mask nearest-rot gather (row-local reads from permuted M1) ----------
    int b = zz - BB;
    if (!((P.mRot >> b) & 1u)) return;
    const float* src = M1 + (size_t)b*HWSZ;
    float* dst = outMsk + (size_t)b*HWSZ;
    int X0 = bx*32, Y0 = by*32;
    #pragma unroll
    for (int k = 0; k < 4; ++k){
      int x = X0 + tx, y = Y0 + ty + 8*k;
      float dx = __fsub_rn((float)x, 255.5f);
      float dy = __fsub_rn((float)y, 255.5f);
      float sx = __fadd_rn(__fadd_rn(__fmul_rn(P.rotC, dx), __fmul_rn(P.rotS, dy)), 255.5f);
      float sy = __fadd_rn(__fadd_rn(__fmul_rn(-P.rotS, dx), __fmul_rn(P.rotC, dy)), 255.5f);
      float xi = rintf(sx), yi = rintf(sy);
      bool valid = (xi >= 0.0f) && (xi < 512.0f) && (yi >= 0.0f) && (yi < 512.0f);
      int xc = (int)fminf(fmaxf(xi, 0.0f), 511.0f);
      int yc = (int)fminf(fmaxf(yi, 0.0f), 511.0f);
      float v = valid ? src[yc*512 + xc] : 0.0f;
      dst[y*512 + x] = v;
    }
    return;
  }

  // ---------- image final ----------
  int b = zz;
  const float W1 = 1.0f/13.0f, W5 = 5.0f/13.0f;
  bool fl  = (P.mFlip  >> b) & 1u;
  bool r9  = (P.mRot90 >> b) & 1u;
  bool tr  = (P.mTrans >> b) & 1u;
  bool rot = (P.mRot   >> b) & 1u;
  bool hue = (P.mHue   >> b) & 1u;
  bool bri = (P.mBri   >> b) & 1u;
  bool con = (P.mCon   >> b) & 1u;
  bool sat = (P.mSat   >> b) & 1u;
  bool shg = (P.mSharp >> b) & 1u;
  bool noi = (P.mNoise >> b) & 1u;
  float mean = meanAcc[b] * (1.0f/262144.0f);
  float cadd = (1.0f - P.con) * mean;
  const float* s1b = S1 + (size_t)b*CHW;
  const float* imb = img + (size_t)b*CHW;

  if (!shg && !rot && !r9 && !tr){
    // pointwise float4 path directly from input
    int row = tid >> 3, q = tid & 7;
    int y = by*32 + row; int x4 = bx*32 + q*4;
    float4 rv, gv, bv;
    if (!fl){
      rv = *(const float4*)(imb + y*512 + x4);
      gv = *(const float4*)(imb + HWSZ + y*512 + x4);
      bv = *(const float4*)(imb + 2*HWSZ + y*512 + x4);
    } else {
      float4 rw = *(const float4*)(imb + y*512 + (508 - x4));
      float4 gw = *(const float4*)(imb + HWSZ + y*512 + (508 - x4));
      float4 bw = *(const float4*)(imb + 2*HWSZ + y*512 + (508 - x4));
      rv = make_float4(rw.w, rw.z, rw.y, rw.x);
      gv = make_float4(gw.w, gw.z, gw.y, gw.x);
      bv = make_float4(bw.w, bw.z, bw.y, bw.x);
    }
    float R[4] = {rv.x, rv.y, rv.z, rv.w};
    float G[4] = {gv.x, gv.y, gv.z, gv.w};
    float B[4] = {bv.x, bv.y, bv.z, bv.w};
    float O[3][4];
    #pragma unroll
    for (int e = 0; e < 4; ++e){
      float v[3] = {(R[e]+1.0f)*0.5f, (G[e]+1.0f)*0.5f, (B[e]+1.0f)*0.5f};
      applyHB(v, hue, bri, P);
      procCS(v, con, P.con, cadd, sat, P.sat);
      if (noi){
        #pragma unroll
        for (int c = 0; c < 3; ++c){
          uint32_t idx = (uint32_t)(b*CHW + c*HWSZ + y*512 + x4 + e);
          uint32_t o0, o1;
          tf2x32(P.nk0, P.nk1, 0u, idx, o0, o1);
          v[c] += normal_from_bits(o0 ^ o1) * 0.1f;
        }
      }
      #pragma unroll
      for (int c = 0; c < 3; ++c) O[c][e] = (v[c] - 0.5f) * 2.0f;
    }
    #pragma unroll
    for (int c = 0; c < 3; ++c){
      float4 w = make_float4(O[c][0], O[c][1], O[c][2], O[c][3]);
      *(float4*)(out + (size_t)b*CHW + (size_t)c*HWSZ + (size_t)y*512 + x4) = w;
    }
    return;   // block-uniform
  }

  if (!shg){
    // no sharpness: scalar per-pixel path, no LDS
    #pragma unroll
    for (int k = 0; k < 4; ++k){
      int x = bx*32 + tx, y = by*32 + ty + 8*k;
      float res[3];
      if (rot) stage2S1(s1b, y, x, P, b, res);
      else     stage2RGB(imb, y, x, P, b, res);
      procCS(res, con, P.con, cadd, sat, P.sat);
      if (noi){
        #pragma unroll
        for (int c = 0; c < 3; ++c){
          uint32_t idx = (uint32_t)(b*CHW + c*HWSZ + y*512 + x);
          uint32_t o0, o1;
          tf2x32(P.nk0, P.nk1, 0u, idx, o0, o1);
          res[c] += normal_from_bits(o0 ^ o1) * 0.1f;
        }
      }
      #pragma unroll
      for (int c = 0; c < 3; ++c){
        out[(size_t)b*CHW + (size_t)c*HWSZ + (size_t)y*512 + x] = (res[c] - 0.5f) * 2.0f;
      }
    }
    return;   // block-uniform
  }

  // sharpness: stage-2 + con/sat -> LDS halo tile (34x34), sharpen, noise, write
  for (int cell = tid; cell < 34*34; cell += 256){
    int r = cell / 34, cc = cell - r*34;
    int gy = by*32 + r - 1, gx = bx*32 + cc - 1;
    float v[3] = {0.0f, 0.0f, 0.0f};
    if ((unsigned)gx < 512u && (unsigned)gy < 512u){
      if (rot) stage2S1(s1b, gy, gx, P, b, v);
      else     stage2RGB(imb, gy, gx, P, b, v);
      procCS(v, con, P.con, cadd, sat, P.sat);
    }
    s2[r][cc][0] = v[0]; s2[r][cc][1] = v[1]; s2[r][cc][2] = v[2];
  }
  __syncthreads();

  for (int k = 0; k < 4; ++k){
    int yy = ty + 8*k;
    int x = bx*32 + tx, y = by*32 + yy;
    bool interior = (x >= 1) && (x <= 510) && (y >= 1) && (y <= 510);
    float res[3];
    float c0[3] = { s2[yy+1][tx+1][0], s2[yy+1][tx+1][1], s2[yy+1][tx+1][2] };
    if (interior){
      float nsum[3] = {0.0f, 0.0f, 0.0f};
      #pragma unroll
      for (int dy = 0; dy < 3; ++dy){
        #pragma unroll
        for (int dxx = 0; dxx < 3; ++dxx){
          if (dxx == 1 && dy == 1) continue;
          #pragma unroll
          for (int c = 0; c < 3; ++c) nsum[c] += s2[yy+dy][tx+dxx][c];
        }
      }
      #pragma unroll
      for (int c = 0; c < 3; ++c){
        float bl = clip01(nsum[c]*W1 + c0[c]*W5);
        res[c] = clip01(P.shp * c0[c] + (1.0f - P.shp) * bl);
      }
    } else {
      res[0] = c0[0]; res[1] = c0[1]; res[2] = c0[2];
    }

    if (noi){
      #pragma unroll
      for (int c = 0; c < 3; ++c){
        uint32_t idx = (uint32_t)(b*CHW + c*HWSZ + y*512 + x);
        uint32_t o0, o1;
        tf2x32(P.nk0, P.nk1, 0u, idx, o0, o1);
        res[c] += normal_from_bits(o0 ^ o1) * 0.1f;
      }
    }
    #pragma unroll
    for (int c = 0; c < 3; ++c){
      out[(size_t)b*CHW + (size_t)c*HWSZ + (size_t)y*512 + x] = (res[c] - 0.5f) * 2.0f;
    }
  }
}

// ===== FALLBACK PATH (previous proven kernels) =====

__global__ __launch_bounds__(256) void kMask(const float* __restrict__ msk,
                                             float* __restrict__ out, AugParams P){
  int x = blockIdx.x*blockDim.x + threadIdx.x;
  int y = blockIdx.y*blockDim.y + threadIdx.y;
  int b = blockIdx.z;
  bool fl  = (P.mFlip  >> b) & 1u;
  bool r9  = (P.mRot90 >> b) & 1u;
  bool rot = (P.mRot   >> b) & 1u;
  float v;
  if (rot){
    float dx = __fsub_rn((float)x, 255.5f);
    float dy = __fsub_rn((float)y, 255.5f);
    float sx = __fadd_rn(__fadd_rn(__fmul_rn(P.rotC, dx), __fmul_rn(P.rotS, dy)), 255.5f);
    float sy = __fadd_rn(__fadd_rn(__fmul_rn(-P.rotS, dx), __fmul_rn(P.rotC, dy)), 255.5f);
    float xi = rintf(sx), yi = rintf(sy);
    bool valid = (xi >= 0.0f) && (xi < 512.0f) && (yi >= 0.0f) && (yi < 512.0f);
    int xc = (int)fminf(fmaxf(xi, 0.0f), 511.0f);
    int yc = (int)fminf(fmaxf(yi, 0.0f), 511.0f);
    int py, px; permIdx(yc, xc, r9, fl, py, px);
    v = valid ? msk[(size_t)b*HWSZ + py*512 + px] : 0.0f;
  } else {
    int py, px; permIdx(y, x, r9, fl, py, px);
    v = msk[(size_t)b*HWSZ + py*512 + px];
  }
  out[(size_t)b*HWSZ + y*512 + x] = v;
}

__global__ __launch_bounds__(256) void kMean(const float* __restrict__ img,
                                             float* __restrict__ meanAcc, AugParams P){
  int b = blockIdx.z;
  if (!((P.mCon >> b) & 1u)) return;
  int x = blockIdx.x*blockDim.x + threadIdx.x;
  int y = blockIdx.y*blockDim.y + threadIdx.y;
  float v[3];
  stage2RGB(img + (size_t)b*CHW, y, x, P, b, v);
  float gray = 0.2989f*v[0] + 0.587f*v[1] + 0.114f*v[2];
  __shared__ float sred[256];
  int tid = threadIdx.y*blockDim.x + threadIdx.x;
  sred[tid] = gray;
  __syncthreads();
  for (int s = 128; s > 0; s >>= 1){
    if (tid < s) sred[tid] += sred[tid + s];
    __syncthreads();
  }
  if (tid == 0) atomicAdd(&meanAcc[b], sred[0]);
}

__global__ __launch_bounds__(256) void kFinal(const float* __restrict__ img,
                                              const float* __restrict__ meanAcc,
                                              float* __restrict__ out, AugParams P){
  __shared__ float s2[10][34][3];
  int tx = threadIdx.x, ty = threadIdx.y;
  int tid = ty*32 + tx;
  int bx = blockIdx.x, by = blockIdx.y, b = blockIdx.z;
  const float W1 = 1.0f/13.0f, W5 = 5.0f/13.0f;

  bool con = (P.mCon   >> b) & 1u;
  bool sat = (P.mSat   >> b) & 1u;
  bool shg = (P.mSharp >> b) & 1u;
  bool noi = (P.mNoise >> b) & 1u;
  float mean = meanAcc[b] * (1.0f/262144.0f);
  float cadd = (1.0f - P.con) * mean;
  const float* base = img + (size_t)b*CHW;

  for (int cell = tid; cell < 340; cell += 256){
    int r = cell / 34, cc = cell % 34;
    int gy = by*8 + r - 1, gx = bx*32 + cc - 1;
    float v[3] = {0.0f, 0.0f, 0.0f};
    if ((unsigned)gx < 512u && (unsigned)gy < 512u){
      stage2RGB(base, gy, gx, P, b, v);
      procCS(v, con, P.con, cadd, sat, P.sat);
    }
    s2[r][cc][0] = v[0]; s2[r][cc][1] = v[1]; s2[r][cc][2] = v[2];
  }
  __syncthreads();

  int x = bx*32 + tx, y = by*8 + ty;
  bool interior = (x >= 1) && (x <= 510) && (y >= 1) && (y <= 510);
  float res[3];
  float c0[3] = { s2[ty+1][tx+1][0], s2[ty+1][tx+1][1], s2[ty+1][tx+1][2] };
  if (shg && interior){
    float nsum[3] = {0.0f, 0.0f, 0.0f};
    #pragma unroll
    for (int dy = 0; dy < 3; ++dy){
      #pragma unroll
      for (int dxx = 0; dxx < 3; ++dxx){
        if (dxx == 1 && dy == 1) continue;
        #pragma unroll
        for (int c = 0; c < 3; ++c) nsum[c] += s2[ty+dy][tx+dxx][c];
      }
    }
    #pragma unroll
    for (int c = 0; c < 3; ++c){
      float bl = clip01(nsum[c]*W1 + c0[c]*W5);
      res[c] = clip01(P.shp * c0[c] + (1.0f - P.shp) * bl);
    }
  } else {
    res[0] = c0[0]; res[1] = c0[1]; res[2] = c0[2];
  }

  if (noi){
    #pragma unroll
    for (int c = 0; c < 3; ++c){
      uint32_t idx = (uint32_t)(b*CHW + c*HWSZ + y*512 + x);
      uint32_t o0, o1;
      tf2x32(P.nk0, P.nk1, 0u, idx, o0, o1);
      res[c] += normal_from_bits(o0 ^ o1) * 0.1f;
    }
  }
  #pragma unroll
  for (int c = 0; c < 3; ++c){
    out[(size_t)b*CHW + (size_t)c*HWSZ + y*512 + x] = (res[c] - 0.5f) * 2.0f;
  }
}

// ---------------- launch ----------------
extern "C" void kernel_launch(void* const* d_in, const int* in_sizes, int n_in,
                              void* d_out, int out_size, void* d_ws, size_t ws_size,
                              hipStream_t stream) {
  (void)in_sizes; (void)n_in; (void)out_size;
  const float* images = (const float*)d_in[0];
  const float* masks  = (const float*)d_in[1];
  float* out_img = (float*)d_out;
  float* out_msk = out_img + (size_t)NIMG;
  float* meanAcc = (float*)d_ws;   // 32 floats (first 256 B of ws)

  Key root; root.a = 0u; root.b = 42u;
  Key ks[18];
  for (uint32_t j = 0; j < 18; ++j) ks[j] = foldSplit(root, j);

  AugParams P;
  P.mFlip  = gate_mask(ks[0]);
  P.mRot90 = gate_mask(ks[1]);
  P.mTrans = gate_mask(ks[2]);
  P.t      = unif_scalar(ks[3]) * 0.125f;
  P.mRot   = gate_mask(ks[4]);
  float r  = unif_scalar(ks[5]) * 10.0f;
  P.mHue   = gate_mask(ks[6]);
  P.hShift = (unif_scalar(ks[7]) - 0.5f) * 0.95f;
  P.mBri   = gate_mask(ks[8]);
  P.bri    = fabsf(1.0f + normal_scalar(ks[9])  * 0.2f);
  P.mCon   = gate_mask(ks[10]);
  P.con    = fabsf(1.0f + normal_scalar(ks[11]) * 0.2f);
  P.mSat   = gate_mask(ks[12]);
  P.sat    = fabsf(1.0f + normal_scalar(ks[13]) * 0.2f);
  P.mSharp = gate_mask(ks[14]);
  P.shp    = fabsf(1.0f + normal_scalar(ks[15]) * 1.0f);
  P.mNoise = gate_mask(ks[16]);
  P.nk0 = ks[17].a; P.nk1 = ks[17].b;

  // t == 0 would need a right halo in kStage1M; translation with t==0 is exact
  // identity (sx == x bit-exactly), so just clear the gate.
  if (!(P.t > 0.0f)) P.mTrans = 0u;

  float th = r * 0.017453292519943295f;   // single f32 multiply (match XLA deg2rad)
  P.rotC = (float)cos((double)th);
  P.rotS = (float)sin((double)th);

  dim3 blk(32, 8, 1);
  const size_t needFull = ((size_t)NIMG + (size_t)NMSK + 64) * sizeof(float);
  const size_t needImg  = ((size_t)NIMG + 64) * sizeof(float);

  hipMemsetAsync(meanAcc, 0, 32*sizeof(float), stream);

  if (ws_size >= needFull){
    float* S1 = (float*)d_ws + 64;
    float* M1 = S1 + (size_t)NIMG;
    kStage1M<<<dim3(16, 16, 64), blk, 0, stream>>>(images, masks, S1, M1, out_msk, meanAcc, P);
    kMean2  <<<dim3(64, 1, 32), dim3(256,1,1), 0, stream>>>(S1, meanAcc, P);
    kFinalM <<<dim3(16, 16, 64), blk, 0, stream>>>(images, S1, M1, meanAcc, out_img, out_msk, P);
  } else if (ws_size >= needImg){
    float* S1 = (float*)d_ws + 64;
    kMask   <<<dim3(16, 64, 32), blk, 0, stream>>>(masks, out_msk, P);
    kStage1M<<<dim3(16, 16, 32), blk, 0, stream>>>(images, masks, S1, nullptr, out_msk, meanAcc, P);
    kMean2  <<<dim3(64, 1, 32), dim3(256,1,1), 0, stream>>>(S1, meanAcc, P);
    kFinalM <<<dim3(16, 16, 32), blk, 0, stream>>>(images, S1, nullptr, meanAcc, out_img, out_msk, P);
  } else {
    kMask <<<dim3(16, 64, 32), blk, 0, stream>>>(masks, out_msk, P);
    kMean <<<dim3(16, 64, 32), blk, 0, stream>>>(images, meanAcc, P);
    kFinal<<<dim3(16, 64, 32), blk, 0, stream>>>(images, meanAcc, out_img, P);
  }
}

// Round 7
// 357.768 us; speedup vs baseline: 1.0844x; 1.0844x over previous
//
#include <hip/hip_runtime.h>
#include <stdint.h>
#include <math.h>

#define HH 512
#define WW 512
#define BB 32
#define CC 3
#define HWSZ (HH*WW)            // 262144
#define CHW (CC*HWSZ)           // 786432
#define NIMG (BB*CHW)           // 25165824
#define NMSK (BB*HWSZ)          // 8388608

// ---------------- Threefry-2x32 core ----------------
__host__ __device__ inline uint32_t rotl32(uint32_t x, uint32_t r){ return (x<<r)|(x>>(32u-r)); }

__host__ __device__ inline void tf2x32(uint32_t k0, uint32_t k1, uint32_t x0, uint32_t x1,
                                       uint32_t& o0, uint32_t& o1){
  uint32_t kx = k0 ^ k1 ^ 0x1BD11BDAu;
  uint32_t ks[3] = {k0, k1, kx};
  const uint32_t R[2][4] = {{13u,15u,26u,6u},{17u,29u,16u,24u}};
  x0 += ks[0]; x1 += ks[1];
  #pragma unroll
  for (int i = 0; i < 5; ++i){
    #pragma unroll
    for (int j = 0; j < 4; ++j){
      x0 += x1; x1 = rotl32(x1, R[i & 1][j]); x1 ^= x0;
    }
    x0 += ks[(i+1)%3];
    x1 += ks[(i+2)%3] + (uint32_t)(i+1);
  }
  o0 = x0; o1 = x1;
}

__host__ __device__ inline float bits_to_u01(uint32_t b){
  uint32_t fb = (b >> 9) | 0x3f800000u;
  float f;
#ifdef __HIP_DEVICE_COMPILE__
  f = __uint_as_float(fb);
#else
  union { uint32_t u; float f; } cv; cv.u = fb; f = cv.f;
#endif
  return f - 1.0f;
}

// XLA f32 ErfInv polynomial
__host__ __device__ inline float erfinv_f32(float x){
  float w = -log1pf(-x*x);
  float p;
  if (w < 5.0f){
    w -= 2.5f;
    p = 2.81022636e-08f;
    p = fmaf(p, w, 3.43273939e-07f);
    p = fmaf(p, w, -3.5233877e-06f);
    p = fmaf(p, w, -4.39150654e-06f);
    p = fmaf(p, w, 0.00021858087f);
    p = fmaf(p, w, -0.00125372503f);
    p = fmaf(p, w, -0.00417768164f);
    p = fmaf(p, w, 0.246640727f);
    p = fmaf(p, w, 1.50140941f);
  } else {
    w = sqrtf(w) - 3.0f;
    p = -0.000200214257f;
    p = fmaf(p, w, 0.000100950558f);
    p = fmaf(p, w, 0.00134934322f);
    p = fmaf(p, w, -0.00367342844f);
    p = fmaf(p, w, 0.00573950773f);
    p = fmaf(p, w, -0.0076224613f);
    p = fmaf(p, w, 0.00943887047f);
    p = fmaf(p, w, 1.00167406f);
    p = fmaf(p, w, 2.83297682f);
  }
  return p * x;
}

#define NRM_LO (-0.9999999403953552f)   /* nextafterf(-1,0) */
#define SQRT2F 1.41421356237309504880f

__host__ __device__ inline float normal_from_bits(uint32_t b){
  float f = bits_to_u01(b);
  float val = f * 2.0f + NRM_LO;    // (hi-lo) rounds to exactly 2.0f
  val = fmaxf(NRM_LO, val);
  return SQRT2F * erfinv_f32(val);
}

// ---------------- host-side jax.random (PARTITIONABLE threefry) ----------------
struct Key { uint32_t a, b; };

static Key foldSplit(Key k, uint32_t j){
  Key r; tf2x32(k.a, k.b, 0u, j, r.a, r.b); return r;
}

static uint32_t bits32(Key k, uint32_t i){
  uint32_t o0, o1; tf2x32(k.a, k.b, 0u, i, o0, o1); return o0 ^ o1;
}

static float unif_scalar(Key k){ return bits_to_u01(bits32(k, 0u)); }
static float normal_scalar(Key k){ return normal_from_bits(bits32(k, 0u)); }

static uint32_t gate_mask(Key kg){
  Key k1 = foldSplit(kg, 0u);
  Key k2 = foldSplit(kg, 1u);
  Key kl = foldSplit(k1, 1u);           // lower-bits key (second subkey)
  float u = bits_to_u01(bits32(k2, 0u));
  uint32_t m = 0;
  for (uint32_t i = 0; i < 32; ++i){
    float bern = (float)(bits32(kl, i) & 1u);
    if (bern * 0.8f > u) m |= (1u << i);
  }
  return m;
}

// ---------------- params ----------------
struct AugParams {
  uint32_t mFlip, mRot90, mTrans, mRot, mHue, mBri, mCon, mSat, mSharp, mNoise;
  float t, rotC, rotS, hShift, bri, con, sat, shp;
  uint32_t nk0, nk1;
};

// ---------------- device helpers ----------------
__device__ inline float clip01(float v){ return fminf(fmaxf(v, 0.0f), 1.0f); }

__device__ inline void permIdx(int y, int x, bool r9, bool fl, int& py, int& px){
  if (r9){ py = x; px = 511 - y; } else { py = y; px = x; }
  if (fl) px = 511 - px;
}

__device__ inline float tapP(const float* __restrict__ src, int y, int x, bool r9, bool fl){
  if ((unsigned)x >= 512u || (unsigned)y >= 512u) return 0.0f;
  int py, px; permIdx(y, x, r9, fl, py, px);
  return (src[py*512 + px] + 1.0f) * 0.5f;
}

// stage-1 (translate ∘ perm ∘ normalize), (ty,tx) in [0,512)
__device__ inline void stage1RGB(const float* __restrict__ base, int ty, int tx,
                                 bool r9, bool fl, bool tr, float t, float out[3]){
  if (!tr){
    #pragma unroll
    for (int c = 0; c < 3; ++c) out[c] = tapP(base + c*HWSZ, ty, tx, r9, fl);
    return;
  }
  float sx = (((float)tx - 255.5f) - t) + 255.5f;
  float sy = (((float)ty - 255.5f) - t) + 255.5f;
  float x0f = floorf(sx), y0f = floorf(sy);
  float wx = sx - x0f, wy = sy - y0f;
  int x0 = (int)x0f, y0 = (int)y0f;
  #pragma unroll
  for (int c = 0; c < 3; ++c){
    const float* s = base + c*HWSZ;
    float v00 = tapP(s, y0,   x0,   r9, fl);
    float v01 = tapP(s, y0,   x0+1, r9, fl);
    float v10 = tapP(s, y0+1, x0,   r9, fl);
    float v11 = tapP(s, y0+1, x0+1, r9, fl);
    float top = v00*(1.0f-wx) + v01*wx;
    float bot = v10*(1.0f-wx) + v11*wx;
    out[c] = top*(1.0f-wy) + bot*wy;
  }
}

__device__ inline void rotTap(const float* __restrict__ base, int ty, int tx,
                              bool r9, bool fl, bool tr, float t, float o[3]){
  if ((unsigned)tx < 512u && (unsigned)ty < 512u){
    stage1RGB(base, ty, tx, r9, fl, tr, t, o);
  } else {
    o[0] = o[1] = o[2] = 0.0f;
  }
}

// branchless (cndmask) HSV conversions — selection among identically-computed
// candidates, bit-exact vs. the if/else versions.
__device__ inline void rgb2hsv(float r, float g, float b, float& h, float& s, float& v){
  float maxc = fmaxf(fmaxf(r, g), b);
  float minc = fminf(fminf(r, g), b);
  float cr = maxc - minc;
  s = cr / ((maxc == 0.0f) ? 1.0f : maxc);
  float crd = (cr == 0.0f) ? 1.0f : cr;
  float rc = (maxc - r) / crd;
  float gc = (maxc - g) / crd;
  float bc = (maxc - b) / crd;
  float hh = (maxc == r) ? (bc - gc) : ((maxc == g) ? (2.0f + rc - bc) : (4.0f + gc - rc));
  float hd = hh / 6.0f;
  hd = hd - floorf(hd);
  h = (cr == 0.0f) ? 0.0f : hd;
  v = maxc;
}

__device__ inline void hsv2rgb(float h, float s, float v, float& r, float& g, float& b){
  float i = floorf(h * 6.0f);
  float f = h * 6.0f - i;
  float p = v * (1.0f - s);
  float q = v * (1.0f - f * s);
  float t = v * (1.0f - (1.0f - f) * s);
  int ii = ((int)i) % 6;
  r = (ii == 0 || ii == 5) ? v : (ii == 1) ? q : (ii == 4) ? t : p;
  g = (ii == 0) ? t : (ii <= 2) ? v : (ii == 3) ? q : p;
  b = (ii <= 1) ? p : (ii == 2) ? t : (ii <= 4) ? v : q;
}

// hue+brightness on a pixel already in stage-1 space
__device__ inline void applyHB(float v[3], bool hue, bool bri, const AugParams& P){
  if (hue){
    float r = clip01(v[0]), g = clip01(v[1]), bb = clip01(v[2]);
    float h, s, val;
    rgb2hsv(r, g, bb, h, s, val);
    h = h + P.hShift;
    h = h - floorf(h);
    hsv2rgb(h, s, val, v[0], v[1], v[2]);
  }
  if (bri){
    #pragma unroll
    for (int c = 0; c < 3; ++c) v[c] = clip01(v[c] * P.bri);
  }
}

// stage-2: perm+translate+rotate+hue+brightness, straight from input
__device__ inline void stage2RGB(const float* __restrict__ base, int yy, int xx,
                                 const AugParams& P, int b, float v[3]){
  bool fl  = (P.mFlip  >> b) & 1u;
  bool r9  = (P.mRot90 >> b) & 1u;
  bool tr  = (P.mTrans >> b) & 1u;
  bool rot = (P.mRot   >> b) & 1u;
  if (rot){
    float dx = (float)xx - 255.5f;
    float dy = (float)yy - 255.5f;
    float sx = (P.rotC*dx + P.rotS*dy) + 255.5f;
    float sy = (-P.rotS*dx + P.rotC*dy) + 255.5f;
    float x0f = floorf(sx), y0f = floorf(sy);
    float wx = sx - x0f, wy = sy - y0f;
    int x0 = (int)x0f, y0 = (int)y0f;
    float q00[3], q01[3], q10[3], q11[3];
    rotTap(base, y0,   x0,   r9, fl, tr, P.t, q00);
    rotTap(base, y0,   x0+1, r9, fl, tr, P.t, q01);
    rotTap(base, y0+1, x0,   r9, fl, tr, P.t, q10);
    rotTap(base, y0+1, x0+1, r9, fl, tr, P.t, q11);
    #pragma unroll
    for (int c = 0; c < 3; ++c){
      float top = q00[c]*(1.0f-wx) + q01[c]*wx;
      float bot = q10[c]*(1.0f-wx) + q11[c]*wx;
      v[c] = top*(1.0f-wy) + bot*wy;
    }
  } else {
    stage1RGB(base, yy, xx, r9, fl, tr, P.t, v);
  }
  applyHB(v, (P.mHue >> b) & 1u, (P.mBri >> b) & 1u, P);
}

// stage-2 reading materialized stage-1 buffer: rot gather is row-local.
__device__ inline float s1at(const float* __restrict__ s, int y, int x){
  return ((unsigned)x < 512u && (unsigned)y < 512u) ? s[y*512 + x] : 0.0f;
}

__device__ inline void stage2S1(const float* __restrict__ s1b, int yy, int xx,
                                const AugParams& P, int b, float v[3]){
  bool rot = (P.mRot >> b) & 1u;
  bool hue = (P.mHue >> b) & 1u;
  bool bri = (P.mBri >> b) & 1u;
  if (rot){
    float dx = (float)xx - 255.5f;
    float dy = (float)yy - 255.5f;
    float sx = (P.rotC*dx + P.rotS*dy) + 255.5f;
    float sy = (-P.rotS*dx + P.rotC*dy) + 255.5f;
    float x0f = floorf(sx), y0f = floorf(sy);
    float wx = sx - x0f, wy = sy - y0f;
    int x0 = (int)x0f, y0 = (int)y0f;
    #pragma unroll
    for (int c = 0; c < 3; ++c){
      const float* s = s1b + c*HWSZ;
      float v00 = s1at(s, y0,   x0);
      float v01 = s1at(s, y0,   x0+1);
      float v10 = s1at(s, y0+1, x0);
      float v11 = s1at(s, y0+1, x0+1);
      float top = v00*(1.0f-wx) + v01*wx;
      float bot = v10*(1.0f-wx) + v11*wx;
      v[c] = top*(1.0f-wy) + bot*wy;
    }
  } else {
    #pragma unroll
    for (int c = 0; c < 3; ++c) v[c] = s1b[c*HWSZ + yy*512 + xx];
  }
  applyHB(v, hue, bri, P);
}

__device__ inline void procCS(float v[3], bool con, float cmul, float cadd, bool sat, float smul){
  if (con){
    #pragma unroll
    for (int c = 0; c < 3; ++c) v[c] = clip01(cmul * v[c] + cadd);
  }
  if (sat){
    float g = 0.2989f*v[0] + 0.587f*v[1] + 0.114f*v[2];
    float gadd = (1.0f - smul) * g;
    #pragma unroll
    for (int c = 0; c < 3; ++c) v[c] = clip01(smul * v[c] + gadd);
  }
}

// skipMat: batches where stage-1 is a coalesced pointwise map (no r9, no tr) —
// no S1 materialization needed; kFinalM reads the input directly.
__device__ inline bool skipMat(const AugParams& P, int b){
  bool r9  = (P.mRot90 >> b) & 1u;
  bool tr  = (P.mTrans >> b) & 1u;
  bool rot = (P.mRot   >> b) & 1u;
  return !r9 && !tr && !rot;
}

// ---------------- kernels ----------------

// ===== FAST PATH =====

// K1: fused stage-1 image (z<32) + mask stage (z>=32).
// Image batches:
//   skipMat && con : read-only float4 mean (flip-invariant sum; no stores)
//   skipMat && !con: nothing
//   else           : materialize S1 (+ fused mean when con && !rot)
__global__ __launch_bounds__(256) void kStage1M(const float* __restrict__ img,
                                                const float* __restrict__ msk,
                                                float* __restrict__ S1,
                                                float* __restrict__ M1,
                                                float* __restrict__ outMsk,
                                                float* __restrict__ meanAcc, AugParams P){
  __shared__ float ptile[3][33][33];
  __shared__ float wsum[4];
  int zz = blockIdx.z;
  int tx = threadIdx.x, ty = threadIdx.y;
  int tid = ty*32 + tx;
  int X0 = blockIdx.x*32, Y0 = blockIdx.y*32;

  if (zz >= BB){
    // ---------- mask stage ----------
    int b = zz - BB;
    bool fl  = (P.mFlip  >> b) & 1u;
    bool r9  = (P.mRot90 >> b) & 1u;
    bool rot = (P.mRot   >> b) & 1u;
    const float* src = msk + (size_t)b*HWSZ;
    float* dst = (rot ? M1 : outMsk) + (size_t)b*HWSZ;
    if (!r9){
      int row = tid >> 3, q = tid & 7;
      int y = Y0 + row, x4 = X0 + q*4;
      float4 u;
      if (!fl){
        u = *(const float4*)(src + y*512 + x4);
      } else {
        float4 w = *(const float4*)(src + y*512 + (508 - x4));
        u = make_float4(w.w, w.z, w.y, w.x);
      }
      *(float4*)(dst + y*512 + x4) = u;
    } else {
      float (*mtile)[33] = reinterpret_cast<float(*)[33]>(&ptile[0][0][0]);
      for (int idx = tid; idx < 32*32; idx += 256){
        int r = idx >> 5, q = idx & 31;
        int xx = X0 + r;                  // output col == src row
        int yy = Y0 + q;                  // output row -> src col
        int col = fl ? yy : (511 - yy);
        mtile[q][r] = src[xx*512 + col];
      }
      __syncthreads();
      #pragma unroll
      for (int k = 0; k < 4; ++k){
        int y = Y0 + ty + 8*k, x = X0 + tx;
        dst[y*512 + x] = mtile[ty + 8*k][tx];
      }
    }
    return;
  }

  // ---------- image ----------
  int b = zz;
  bool fl  = (P.mFlip  >> b) & 1u;
  bool r9  = (P.mRot90 >> b) & 1u;
  bool tr  = (P.mTrans >> b) & 1u;
  bool rot = (P.mRot   >> b) & 1u;
  bool con = (P.mCon   >> b) & 1u;
  bool hue = (P.mHue   >> b) & 1u;
  bool bri = (P.mBri   >> b) & 1u;
  const float* base = img + (size_t)b*CHW;
  float t = P.t;
  float gsum = 0.0f;

  if (!r9 && !tr && !rot){
    // skipMat: no materialization. Mean only (flip is a pixel permutation —
    // the sum is flip-invariant, so read unflipped, fully coalesced).
    if (!con) return;
    int row = tid >> 3, q = tid & 7;
    int y = Y0 + row, x4 = X0 + q*4;
    float4 rv = *(const float4*)(base + y*512 + x4);
    float4 gv = *(const float4*)(base + HWSZ + y*512 + x4);
    float4 bv = *(const float4*)(base + 2*HWSZ + y*512 + x4);
    float R[4] = {rv.x, rv.y, rv.z, rv.w};
    float G[4] = {gv.x, gv.y, gv.z, gv.w};
    float B[4] = {bv.x, bv.y, bv.z, bv.w};
    #pragma unroll
    for (int e = 0; e < 4; ++e){
      float w[3] = {(R[e]+1.0f)*0.5f, (G[e]+1.0f)*0.5f, (B[e]+1.0f)*0.5f};
      applyHB(w, hue, bri, P);
      gsum += 0.2989f*w[0] + 0.587f*w[1] + 0.114f*w[2];
    }
    #pragma unroll
    for (int off = 32; off > 0; off >>= 1) gsum += __shfl_down(gsum, off);
    int wid = tid >> 6, lid = tid & 63;
    if (lid == 0) wsum[wid] = gsum;
    __syncthreads();
    if (tid == 0) atomicAdd(&meanAcc[b], wsum[0] + wsum[1] + wsum[2] + wsum[3]);
    return;
  }

  // materialize S1 (+ fused mean for con && !rot)
  bool accM = con && !rot;           // block-uniform
  float* dstb = S1 + (size_t)b*CHW;

  if (!r9 && !tr){
    // (rot batches with plain/flip perm) float4 permuted copy
    int row = tid >> 3, q = tid & 7;
    int y = Y0 + row, x4 = X0 + q*4;
    #pragma unroll
    for (int c = 0; c < 3; ++c){
      float4 u;
      if (!fl){
        u = *(const float4*)(base + c*HWSZ + y*512 + x4);
      } else {
        float4 w = *(const float4*)(base + c*HWSZ + y*512 + (508 - x4));
        u = make_float4(w.w, w.z, w.y, w.x);
      }
      u.x = (u.x + 1.0f)*0.5f; u.y = (u.y + 1.0f)*0.5f;
      u.z = (u.z + 1.0f)*0.5f; u.w = (u.w + 1.0f)*0.5f;
      *(float4*)(dstb + c*HWSZ + y*512 + x4) = u;
    }
  } else if (!r9){
    // translate-only (identical arithmetic to stage1RGB)
    #pragma unroll
    for (int k = 0; k < 4; ++k){
      int y = Y0 + ty + 8*k, x = X0 + tx;
      float v[3];
      stage1RGB(base, y, x, false, fl, true, t, v);
      #pragma unroll
      for (int c = 0; c < 3; ++c)
        dstb[(size_t)c*HWSZ + (size_t)y*512 + x] = v[c];
      if (accM){
        float w[3] = {v[0], v[1], v[2]};
        applyHB(w, hue, bri, P);
        gsum += 0.2989f*w[0] + 0.587f*w[1] + 0.114f*w[2];
      }
    }
  } else {
    // r9 (optionally + tr): staged LDS transpose, all channels, single barrier
    #pragma unroll
    for (int c = 0; c < 3; ++c){
      const float* src = base + c*HWSZ;
      for (int idx = tid; idx < 33*33; idx += 256){
        int r = idx / 33, q = idx - r*33;
        int xx = X0 - 1 + r;      // output col == src row
        int yy = Y0 - 1 + q;      // output row -> src col
        float val = 0.0f;
        if ((unsigned)yy < 512u && (unsigned)xx < 512u){
          int col = fl ? yy : (511 - yy);
          val = (src[xx*512 + col] + 1.0f) * 0.5f;
        }
        ptile[c][q][r] = val;     // transpose store
      }
    }
    __syncthreads();
    #pragma unroll
    for (int k = 0; k < 4; ++k){
      int y = Y0 + ty + 8*k, x = X0 + tx;
      float v[3];
      if (tr){
        float sx = (((float)x - 255.5f) - t) + 255.5f;
        float sy = (((float)y - 255.5f) - t) + 255.5f;
        float x0f = floorf(sx), y0f = floorf(sy);
        float wx = sx - x0f, wy = sy - y0f;
        int lx0 = (int)x0f - (X0 - 1);
        int ly0 = (int)y0f - (Y0 - 1);
        #pragma unroll
        for (int c = 0; c < 3; ++c){
          float v00 = ptile[c][ly0][lx0],   v01 = ptile[c][ly0][lx0+1];
          float v10 = ptile[c][ly0+1][lx0], v11 = ptile[c][ly0+1][lx0+1];
          float top = v00*(1.0f-wx) + v01*wx;
          float bot = v10*(1.0f-wx) + v11*wx;
          v[c] = top*(1.0f-wy) + bot*wy;
        }
      } else {
        #pragma unroll
        for (int c = 0; c < 3; ++c) v[c] = ptile[c][ty+8*k+1][tx+1];
      }
      #pragma unroll
      for (int c = 0; c < 3; ++c)
        dstb[(size_t)c*HWSZ + (size_t)y*512 + x] = v[c];
      if (accM){
        float w[3] = {v[0], v[1], v[2]};
        applyHB(w, hue, bri, P);
        gsum += 0.2989f*w[0] + 0.587f*w[1] + 0.114f*w[2];
      }
    }
  }

  if (accM){
    #pragma unroll
    for (int off = 32; off > 0; off >>= 1) gsum += __shfl_down(gsum, off);
    int wid = tid >> 6, lid = tid & 63;
    if (lid == 0) wsum[wid] = gsum;
    __syncthreads();
    if (tid == 0) atomicAdd(&meanAcc[b], wsum[0] + wsum[1] + wsum[2] + wsum[3]);
  }
}

// K2: contrast mean for rot && con batches (from S1, row-local gather).
// 256 blocks/batch, 4 px/thread: ~4x more blocks than before for latency hiding.
__global__ __launch_bounds__(256) void kMean2(const float* __restrict__ S1,
                                              float* __restrict__ meanAcc, AugParams P){
  int b = blockIdx.z;
  if (!((P.mCon >> b) & 1u) || !((P.mRot >> b) & 1u)) return;
  int tid = threadIdx.x;                 // 256 threads, 1-D block
  const float* base = S1 + (size_t)b*CHW;
  int pbase = blockIdx.x * 1024;         // 256 blocks cover 262144 px
  float lsum = 0.0f;

  #pragma unroll
  for (int j = 0; j < 4; ++j){
    int px = pbase + j*256 + tid;
    int y = px >> 9, x = px & 511;
    float v[3];
    stage2S1(base, y, x, P, b, v);
    lsum += 0.2989f*v[0] + 0.587f*v[1] + 0.114f*v[2];
  }

  #pragma unroll
  for (int off = 32; off > 0; off >>= 1) lsum += __shfl_down(lsum, off);
  __shared__ float wsum[4];
  int wid = tid >> 6, lid = tid & 63;
  if (lid == 0) wsum[wid] = lsum;
  __syncthreads();
  if (tid == 0) atomicAdd(&meanAcc[b], wsum[0] + wsum[1] + wsum[2] + wsum[3]);
}

// K3: fused final image (z<32) + mask nearest-rotation (z>=32).
// skipMat batches read the input directly (coalesced pointwise); all others read S1.
__global__ __launch_bounds__(256) void kFinalM(const float* __restrict__ img,
                                               const float* __restrict__ S1,
                                               const float* __restrict__ M1,
                                               const float* __restrict__ meanAcc,
                                               float* __restrict__ out,
                                               float* __restrict__ outMsk, AugParams P){
  __shared__ float s2[34][34][3];
  int zz = blockIdx.z;
  int tx = threadIdx.x, ty = threadIdx.y;
  int tid = ty*32 + tx;
  int bx = blockIdx.x, by = blockIdx.y;

  if (zz >= BB){
    // ---------- mask nearest-rot gather (row-local reads from permuted M1) ----------
    int b = zz - BB;
    if (!((P.mRot >> b) & 1u)) return;
    const float* src = M1 + (size_t)b*HWSZ;
    float* dst = outMsk + (size_t)b*HWSZ;
    int X0 = bx*32, Y0 = by*32;
    #pragma unroll
    for (int k = 0; k < 4; ++k){
      int x = X0 + tx, y = Y0 + ty + 8*k;
      float dx = __fsub_rn((float)x, 255.5f);
      float dy = __fsub_rn((float)y, 255.5f);
      float sx = __fadd_rn(__fadd_rn(__fmul_rn(P.rotC, dx), __fmul_rn(P.rotS, dy)), 255.5f);
      float sy = __fadd_rn(__fadd_rn(__fmul_rn(-P.rotS, dx), __fmul_rn(P.rotC, dy)), 255.5f);
      float xi = rintf(sx), yi = rintf(sy);
      bool valid = (xi >= 0.0f) && (xi < 512.0f) && (yi >= 0.0f) && (yi < 512.0f);
      int xc = (int)fminf(fmaxf(xi, 0.0f), 511.0f);
      int yc = (int)fminf(fmaxf(yi, 0.0f), 511.0f);
      float v = valid ? src[yc*512 + xc] : 0.0f;
      dst[y*512 + x] = v;
    }
    return;
  }

  // ---------- image final ----------
  int b = zz;
  const float W1 = 1.0f/13.0f, W5 = 5.0f/13.0f;
  bool fl  = (P.mFlip  >> b) & 1u;
  bool rot = (P.mRot   >> b) & 1u;
  bool hue = (P.mHue   >> b) & 1u;
  bool bri = (P.mBri   >> b) & 1u;
  bool con = (P.mCon   >> b) & 1u;
  bool sat = (P.mSat   >> b) & 1u;
  bool shg = (P.mSharp >> b) & 1u;
  bool noi = (P.mNoise >> b) & 1u;
  bool skip = skipMat(P, b);
  float mean = meanAcc[b] * (1.0f/262144.0f);
  float cadd = (1.0f - P.con) * mean;
  const float* s1b = S1 + (size_t)b*CHW;
  const float* imb = img + (size_t)b*CHW;

  if (!shg && (skip || !rot)){
    // pointwise float4 path (skip: from input with flip; else: from S1, already permuted)
    int row = tid >> 3, q = tid & 7;
    int y = by*32 + row; int x4 = bx*32 + q*4;
    float4 rv, gv, bv;
    if (skip){
      if (!fl){
        rv = *(const float4*)(imb + y*512 + x4);
        gv = *(const float4*)(imb + HWSZ + y*512 + x4);
        bv = *(const float4*)(imb + 2*HWSZ + y*512 + x4);
      } else {
        float4 rw = *(const float4*)(imb + y*512 + (508 - x4));
        float4 gw = *(const float4*)(imb + HWSZ + y*512 + (508 - x4));
        float4 bw = *(const float4*)(imb + 2*HWSZ + y*512 + (508 - x4));
        rv = make_float4(rw.w, rw.z, rw.y, rw.x);
        gv = make_float4(gw.w, gw.z, gw.y, gw.x);
        bv = make_float4(bw.w, bw.z, bw.y, bw.x);
      }
      rv.x = (rv.x+1.0f)*0.5f; rv.y = (rv.y+1.0f)*0.5f; rv.z = (rv.z+1.0f)*0.5f; rv.w = (rv.w+1.0f)*0.5f;
      gv.x = (gv.x+1.0f)*0.5f; gv.y = (gv.y+1.0f)*0.5f; gv.z = (gv.z+1.0f)*0.5f; gv.w = (gv.w+1.0f)*0.5f;
      bv.x = (bv.x+1.0f)*0.5f; bv.y = (bv.y+1.0f)*0.5f; bv.z = (bv.z+1.0f)*0.5f; bv.w = (bv.w+1.0f)*0.5f;
    } else {
      rv = *(const float4*)(s1b + y*512 + x4);
      gv = *(const float4*)(s1b + HWSZ + y*512 + x4);
      bv = *(const float4*)(s1b + 2*HWSZ + y*512 + x4);
    }
    float R[4] = {rv.x, rv.y, rv.z, rv.w};
    float G[4] = {gv.x, gv.y, gv.z, gv.w};
    float B[4] = {bv.x, bv.y, bv.z, bv.w};
    float O[3][4];
    #pragma unroll
    for (int e = 0; e < 4; ++e){
      float v[3] = {R[e], G[e], B[e]};
      applyHB(v, hue, bri, P);
      procCS(v, con, P.con, cadd, sat, P.sat);
      if (noi){
        #pragma unroll
        for (int c = 0; c < 3; ++c){
          uint32_t idx = (uint32_t)(b*CHW + c*HWSZ + y*512 + x4 + e);
          uint32_t o0, o1;
          tf2x32(P.nk0, P.nk1, 0u, idx, o0, o1);
          v[c] += normal_from_bits(o0 ^ o1) * 0.1f;
        }
      }
      #pragma unroll
      for (int c = 0; c < 3; ++c) O[c][e] = (v[c] - 0.5f) * 2.0f;
    }
    #pragma unroll
    for (int c = 0; c < 3; ++c){
      float4 w = make_float4(O[c][0], O[c][1], O[c][2], O[c][3]);
      *(float4*)(out + (size_t)b*CHW + (size_t)c*HWSZ + (size_t)y*512 + x4) = w;
    }
    return;   // block-uniform
  }

  if (!shg){
    // rot, no sharpness: scalar rot gather from S1, no LDS
    #pragma unroll
    for (int k = 0; k < 4; ++k){
      int x = bx*32 + tx, y = by*32 + ty + 8*k;
      float res[3];
      stage2S1(s1b, y, x, P, b, res);
      procCS(res, con, P.con, cadd, sat, P.sat);
      if (noi){
        #pragma unroll
        for (int c = 0; c < 3; ++c){
          uint32_t idx = (uint32_t)(b*CHW + c*HWSZ + y*512 + x);
          uint32_t o0, o1;
          tf2x32(P.nk0, P.nk1, 0u, idx, o0, o1);
          res[c] += normal_from_bits(o0 ^ o1) * 0.1f;
        }
      }
      #pragma unroll
      for (int c = 0; c < 3; ++c){
        out[(size_t)b*CHW + (size_t)c*HWSZ + (size_t)y*512 + x] = (res[c] - 0.5f) * 2.0f;
      }
    }
    return;   // block-uniform
  }

  // sharpness: stage-2 + con/sat -> LDS halo tile (34x34), sharpen, noise, write.
  // skip batches source the halo from the input (coalesced pointwise); others from S1.
  for (int cell = tid; cell < 34*34; cell += 256){
    int r = cell / 34, cc = cell - r*34;
    int gy = by*32 + r - 1, gx = bx*32 + cc - 1;
    float v[3] = {0.0f, 0.0f, 0.0f};
    if ((unsigned)gx < 512u && (unsigned)gy < 512u){
      if (skip) stage2RGB(imb, gy, gx, P, b, v);
      else      stage2S1(s1b, gy, gx, P, b, v);
      procCS(v, con, P.con, cadd, sat, P.sat);
    }
    s2[r][cc][0] = v[0]; s2[r][cc][1] = v[1]; s2[r][cc][2] = v[2];
  }
  __syncthreads();

  for (int k = 0; k < 4; ++k){
    int yy = ty + 8*k;
    int x = bx*32 + tx, y = by*32 + yy;
    bool interior = (x >= 1) && (x <= 510) && (y >= 1) && (y <= 510);
    float res[3];
    float c0[3] = { s2[yy+1][tx+1][0], s2[yy+1][tx+1][1], s2[yy+1][tx+1][2] };
    if (interior){
      float nsum[3] = {0.0f, 0.0f, 0.0f};
      #pragma unroll
      for (int dy = 0; dy < 3; ++dy){
        #pragma unroll
        for (int dxx = 0; dxx < 3; ++dxx){
          if (dxx == 1 && dy == 1) continue;
          #pragma unroll
          for (int c = 0; c < 3; ++c) nsum[c] += s2[yy+dy][tx+dxx][c];
        }
      }
      #pragma unroll
      for (int c = 0; c < 3; ++c){
        float bl = clip01(nsum[c]*W1 + c0[c]*W5);
        res[c] = clip01(P.shp * c0[c] + (1.0f - P.shp) * bl);
      }
    } else {
      res[0] = c0[0]; res[1] = c0[1]; res[2] = c0[2];
    }

    if (noi){
      #pragma unroll
      for (int c = 0; c < 3; ++c){
        uint32_t idx = (uint32_t)(b*CHW + c*HWSZ + y*512 + x);
        uint32_t o0, o1;
        tf2x32(P.nk0, P.nk1, 0u, idx, o0, o1);
        res[c] += normal_from_bits(o0 ^ o1) * 0.1f;
      }
    }
    #pragma unroll
    for (int c = 0; c < 3; ++c){
      out[(size_t)b*CHW + (size_t)c*HWSZ + (size_t)y*512 + x] = (res[c] - 0.5f) * 2.0f;
    }
  }
}

// ===== FALLBACK PATH (previous proven kernels) =====

__global__ __launch_bounds__(256) void kMask(const float* __restrict__ msk,
                                             float* __restrict__ out, AugParams P){
  int x = blockIdx.x*blockDim.x + threadIdx.x;
  int y = blockIdx.y*blockDim.y + threadIdx.y;
  int b = blockIdx.z;
  bool fl  = (P.mFlip  >> b) & 1u;
  bool r9  = (P.mRot90 >> b) & 1u;
  bool rot = (P.mRot   >> b) & 1u;
  float v;
  if (rot){
    float dx = __fsub_rn((float)x, 255.5f);
    float dy = __fsub_rn((float)y, 255.5f);
    float sx = __fadd_rn(__fadd_rn(__fmul_rn(P.rotC, dx), __fmul_rn(P.rotS, dy)), 255.5f);
    float sy = __fadd_rn(__fadd_rn(__fmul_rn(-P.rotS, dx), __fmul_rn(P.rotC, dy)), 255.5f);
    float xi = rintf(sx), yi = rintf(sy);
    bool valid = (xi >= 0.0f) && (xi < 512.0f) && (yi >= 0.0f) && (yi < 512.0f);
    int xc = (int)fminf(fmaxf(xi, 0.0f), 511.0f);
    int yc = (int)fminf(fmaxf(yi, 0.0f), 511.0f);
    int py, px; permIdx(yc, xc, r9, fl, py, px);
    v = valid ? msk[(size_t)b*HWSZ + py*512 + px] : 0.0f;
  } else {
    int py, px; permIdx(y, x, r9, fl, py, px);
    v = msk[(size_t)b*HWSZ + py*512 + px];
  }
  out[(size_t)b*HWSZ + y*512 + x] = v;
}

__global__ __launch_bounds__(256) void kMean(const float* __restrict__ img,
                                             float* __restrict__ meanAcc, AugParams P){
  int b = blockIdx.z;
  if (!((P.mCon >> b) & 1u)) return;
  int x = blockIdx.x*blockDim.x + threadIdx.x;
  int y = blockIdx.y*blockDim.y + threadIdx.y;
  float v[3];
  stage2RGB(img + (size_t)b*CHW, y, x, P, b, v);
  float gray = 0.2989f*v[0] + 0.587f*v[1] + 0.114f*v[2];
  __shared__ float sred[256];
  int tid = threadIdx.y*blockDim.x + threadIdx.x;
  sred[tid] = gray;
  __syncthreads();
  for (int s = 128; s > 0; s >>= 1){
    if (tid < s) sred[tid] += sred[tid + s];
    __syncthreads();
  }
  if (tid == 0) atomicAdd(&meanAcc[b], sred[0]);
}

__global__ __launch_bounds__(256) void kFinal(const float* __restrict__ img,
                                              const float* __restrict__ meanAcc,
                                              float* __restrict__ out, AugParams P){
  __shared__ float s2[10][34][3];
  int tx = threadIdx.x, ty = threadIdx.y;
  int tid = ty*32 + tx;
  int bx = blockIdx.x, by = blockIdx.y, b = blockIdx.z;
  const float W1 = 1.0f/13.0f, W5 = 5.0f/13.0f;

  bool con = (P.mCon   >> b) & 1u;
  bool sat = (P.mSat   >> b) & 1u;
  bool shg = (P.mSharp >> b) & 1u;
  bool noi = (P.mNoise >> b) & 1u;
  float mean = meanAcc[b] * (1.0f/262144.0f);
  float cadd = (1.0f - P.con) * mean;
  const float* base = img + (size_t)b*CHW;

  for (int cell = tid; cell < 340; cell += 256){
    int r = cell / 34, cc = cell % 34;
    int gy = by*8 + r - 1, gx = bx*32 + cc - 1;
    float v[3] = {0.0f, 0.0f, 0.0f};
    if ((unsigned)gx < 512u && (unsigned)gy < 512u){
      stage2RGB(base, gy, gx, P, b, v);
      procCS(v, con, P.con, cadd, sat, P.sat);
    }
    s2[r][cc][0] = v[0]; s2[r][cc][1] = v[1]; s2[r][cc][2] = v[2];
  }
  __syncthreads();

  int x = bx*32 + tx, y = by*8 + ty;
  bool interior = (x >= 1) && (x <= 510) && (y >= 1) && (y <= 510);
  float res[3];
  float c0[3] = { s2[ty+1][tx+1][0], s2[ty+1][tx+1][1], s2[ty+1][tx+1][2] };
  if (shg && interior){
    float nsum[3] = {0.0f, 0.0f, 0.0f};
    #pragma unroll
    for (int dy = 0; dy < 3; ++dy){
      #pragma unroll
      for (int dxx = 0; dxx < 3; ++dxx){
        if (dxx == 1 && dy == 1) continue;
        #pragma unroll
        for (int c = 0; c < 3; ++c) nsum[c] += s2[ty+dy][tx+dxx][c];
      }
    }
    #pragma unroll
    for (int c = 0; c < 3; ++c){
      float bl = clip01(nsum[c]*W1 + c0[c]*W5);
      res[c] = clip01(P.shp * c0[c] + (1.0f - P.shp) * bl);
    }
  } else {
    res[0] = c0[0]; res[1] = c0[1]; res[2] = c0[2];
  }

  if (noi){
    #pragma unroll
    for (int c = 0; c < 3; ++c){
      uint32_t idx = (uint32_t)(b*CHW + c*HWSZ + y*512 + x);
      uint32_t o0, o1;
      tf2x32(P.nk0, P.nk1, 0u, idx, o0, o1);
      res[c] += normal_from_bits(o0 ^ o1) * 0.1f;
    }
  }
  #pragma unroll
  for (int c = 0; c < 3; ++c){
    out[(size_t)b*CHW + (size_t)c*HWSZ + y*512 + x] = (res[c] - 0.5f) * 2.0f;
  }
}

// ---------------- launch ----------------
extern "C" void kernel_launch(void* const* d_in, const int* in_sizes, int n_in,
                              void* d_out, int out_size, void* d_ws, size_t ws_size,
                              hipStream_t stream) {
  (void)in_sizes; (void)n_in; (void)out_size;
  const float* images = (const float*)d_in[0];
  const float* masks  = (const float*)d_in[1];
  float* out_img = (float*)d_out;
  float* out_msk = out_img + (size_t)NIMG;
  float* meanAcc = (float*)d_ws;   // 32 floats (first 256 B of ws)

  Key root; root.a = 0u; root.b = 42u;
  Key ks[18];
  for (uint32_t j = 0; j < 18; ++j) ks[j] = foldSplit(root, j);

  AugParams P;
  P.mFlip  = gate_mask(ks[0]);
  P.mRot90 = gate_mask(ks[1]);
  P.mTrans = gate_mask(ks[2]);
  P.t      = unif_scalar(ks[3]) * 0.125f;
  P.mRot   = gate_mask(ks[4]);
  float r  = unif_scalar(ks[5]) * 10.0f;
  P.mHue   = gate_mask(ks[6]);
  P.hShift = (unif_scalar(ks[7]) - 0.5f) * 0.95f;
  P.mBri   = gate_mask(ks[8]);
  P.bri    = fabsf(1.0f + normal_scalar(ks[9])  * 0.2f);
  P.mCon   = gate_mask(ks[10]);
  P.con    = fabsf(1.0f + normal_scalar(ks[11]) * 0.2f);
  P.mSat   = gate_mask(ks[12]);
  P.sat    = fabsf(1.0f + normal_scalar(ks[13]) * 0.2f);
  P.mSharp = gate_mask(ks[14]);
  P.shp    = fabsf(1.0f + normal_scalar(ks[15]) * 1.0f);
  P.mNoise = gate_mask(ks[16]);
  P.nk0 = ks[17].a; P.nk1 = ks[17].b;

  // t == 0 would need a right halo in kStage1M; translation with t==0 is exact
  // identity (sx == x bit-exactly), so just clear the gate.
  if (!(P.t > 0.0f)) P.mTrans = 0u;

  float th = r * 0.017453292519943295f;   // single f32 multiply (match XLA deg2rad)
  P.rotC = (float)cos((double)th);
  P.rotS = (float)sin((double)th);

  dim3 blk(32, 8, 1);
  const size_t needFull = ((size_t)NIMG + (size_t)NMSK + 64) * sizeof(float);
  const size_t needImg  = ((size_t)NIMG + 64) * sizeof(float);

  hipMemsetAsync(meanAcc, 0, 32*sizeof(float), stream);

  if (ws_size >= needFull){
    float* S1 = (float*)d_ws + 64;
    float* M1 = S1 + (size_t)NIMG;
    kStage1M<<<dim3(16, 16, 64), blk, 0, stream>>>(images, masks, S1, M1, out_msk, meanAcc, P);
    kMean2  <<<dim3(256, 1, 32), dim3(256,1,1), 0, stream>>>(S1, meanAcc, P);
    kFinalM <<<dim3(16, 16, 64), blk, 0, stream>>>(images, S1, M1, meanAcc, out_img, out_msk, P);
  } else if (ws_size >= needImg){
    float* S1 = (float*)d_ws + 64;
    kMask   <<<dim3(16, 64, 32), blk, 0, stream>>>(masks, out_msk, P);
    kStage1M<<<dim3(16, 16, 32), blk, 0, stream>>>(images, masks, S1, nullptr, out_msk, meanAcc, P);
    kMean2  <<<dim3(256, 1, 32), dim3(256,1,1), 0, stream>>>(S1, meanAcc, P);
    kFinalM <<<dim3(16, 16, 32), blk, 0, stream>>>(images, S1, nullptr, meanAcc, out_img, out_msk, P);
  } else {
    kMask <<<dim3(16, 64, 32), blk, 0, stream>>>(masks, out_msk, P);
    kMean <<<dim3(16, 64, 32), blk, 0, stream>>>(images, meanAcc, P);
    kFinal<<<dim3(16, 64, 32), blk, 0, stream>>>(images, meanAcc, out_img, P);
  }
}

// Round 8
// 356.304 us; speedup vs baseline: 1.0888x; 1.0041x over previous
//
#include <hip/hip_runtime.h>
#include <stdint.h>
#include <math.h>

#define HH 512
#define WW 512
#define BB 32
#define CC 3
#define HWSZ (HH*WW)            // 262144
#define CHW (CC*HWSZ)           // 786432
#define NIMG (BB*CHW)           // 25165824
#define NMSK (BB*HWSZ)          // 8388608

// ---------------- Threefry-2x32 core ----------------
__host__ __device__ inline uint32_t rotl32(uint32_t x, uint32_t r){ return (x<<r)|(x>>(32u-r)); }

__host__ __device__ inline void tf2x32(uint32_t k0, uint32_t k1, uint32_t x0, uint32_t x1,
                                       uint32_t& o0, uint32_t& o1){
  uint32_t kx = k0 ^ k1 ^ 0x1BD11BDAu;
  uint32_t ks[3] = {k0, k1, kx};
  const uint32_t R[2][4] = {{13u,15u,26u,6u},{17u,29u,16u,24u}};
  x0 += ks[0]; x1 += ks[1];
  #pragma unroll
  for (int i = 0; i < 5; ++i){
    #pragma unroll
    for (int j = 0; j < 4; ++j){
      x0 += x1; x1 = rotl32(x1, R[i & 1][j]); x1 ^= x0;
    }
    x0 += ks[(i+1)%3];
    x1 += ks[(i+2)%3] + (uint32_t)(i+1);
  }
  o0 = x0; o1 = x1;
}

__host__ __device__ inline float bits_to_u01(uint32_t b){
  uint32_t fb = (b >> 9) | 0x3f800000u;
  float f;
#ifdef __HIP_DEVICE_COMPILE__
  f = __uint_as_float(fb);
#else
  union { uint32_t u; float f; } cv; cv.u = fb; f = cv.f;
#endif
  return f - 1.0f;
}

// XLA f32 ErfInv polynomial
__host__ __device__ inline float erfinv_f32(float x){
  float w = -log1pf(-x*x);
  float p;
  if (w < 5.0f){
    w -= 2.5f;
    p = 2.81022636e-08f;
    p = fmaf(p, w, 3.43273939e-07f);
    p = fmaf(p, w, -3.5233877e-06f);
    p = fmaf(p, w, -4.39150654e-06f);
    p = fmaf(p, w, 0.00021858087f);
    p = fmaf(p, w, -0.00125372503f);
    p = fmaf(p, w, -0.00417768164f);
    p = fmaf(p, w, 0.246640727f);
    p = fmaf(p, w, 1.50140941f);
  } else {
    w = sqrtf(w) - 3.0f;
    p = -0.000200214257f;
    p = fmaf(p, w, 0.000100950558f);
    p = fmaf(p, w, 0.00134934322f);
    p = fmaf(p, w, -0.00367342844f);
    p = fmaf(p, w, 0.00573950773f);
    p = fmaf(p, w, -0.0076224613f);
    p = fmaf(p, w, 0.00943887047f);
    p = fmaf(p, w, 1.00167406f);
    p = fmaf(p, w, 2.83297682f);
  }
  return p * x;
}

#define NRM_LO (-0.9999999403953552f)   /* nextafterf(-1,0) */
#define SQRT2F 1.41421356237309504880f

__host__ __device__ inline float normal_from_bits(uint32_t b){
  float f = bits_to_u01(b);
  float val = f * 2.0f + NRM_LO;    // (hi-lo) rounds to exactly 2.0f
  val = fmaxf(NRM_LO, val);
  return SQRT2F * erfinv_f32(val);
}

// ---------------- host-side jax.random (PARTITIONABLE threefry) ----------------
struct Key { uint32_t a, b; };

static Key foldSplit(Key k, uint32_t j){
  Key r; tf2x32(k.a, k.b, 0u, j, r.a, r.b); return r;
}

static uint32_t bits32(Key k, uint32_t i){
  uint32_t o0, o1; tf2x32(k.a, k.b, 0u, i, o0, o1); return o0 ^ o1;
}

static float unif_scalar(Key k){ return bits_to_u01(bits32(k, 0u)); }
static float normal_scalar(Key k){ return normal_from_bits(bits32(k, 0u)); }

static uint32_t gate_mask(Key kg){
  Key k1 = foldSplit(kg, 0u);
  Key k2 = foldSplit(kg, 1u);
  Key kl = foldSplit(k1, 1u);           // lower-bits key (second subkey)
  float u = bits_to_u01(bits32(k2, 0u));
  uint32_t m = 0;
  for (uint32_t i = 0; i < 32; ++i){
    float bern = (float)(bits32(kl, i) & 1u);
    if (bern * 0.8f > u) m |= (1u << i);
  }
  return m;
}

// ---------------- params ----------------
struct AugParams {
  uint32_t mFlip, mRot90, mTrans, mRot, mHue, mBri, mCon, mSat, mSharp, mNoise;
  float t, rotC, rotS, hShift, bri, con, sat, shp;
  uint32_t nk0, nk1;
  uint32_t nMeanB;
  uint8_t  meanList[32];    // dense list of rot&&con batches for kMean2
};

// ---------------- device helpers ----------------
__device__ inline float clip01(float v){ return fminf(fmaxf(v, 0.0f), 1.0f); }

__device__ inline void permIdx(int y, int x, bool r9, bool fl, int& py, int& px){
  if (r9){ py = x; px = 511 - y; } else { py = y; px = x; }
  if (fl) px = 511 - px;
}

__device__ inline float tapP(const float* __restrict__ src, int y, int x, bool r9, bool fl){
  if ((unsigned)x >= 512u || (unsigned)y >= 512u) return 0.0f;
  int py, px; permIdx(y, x, r9, fl, py, px);
  return (src[py*512 + px] + 1.0f) * 0.5f;
}

// stage-1 (translate ∘ perm ∘ normalize), (ty,tx) in [0,512)
__device__ inline void stage1RGB(const float* __restrict__ base, int ty, int tx,
                                 bool r9, bool fl, bool tr, float t, float out[3]){
  if (!tr){
    #pragma unroll
    for (int c = 0; c < 3; ++c) out[c] = tapP(base + c*HWSZ, ty, tx, r9, fl);
    return;
  }
  float sx = (((float)tx - 255.5f) - t) + 255.5f;
  float sy = (((float)ty - 255.5f) - t) + 255.5f;
  float x0f = floorf(sx), y0f = floorf(sy);
  float wx = sx - x0f, wy = sy - y0f;
  int x0 = (int)x0f, y0 = (int)y0f;
  #pragma unroll
  for (int c = 0; c < 3; ++c){
    const float* s = base + c*HWSZ;
    float v00 = tapP(s, y0,   x0,   r9, fl);
    float v01 = tapP(s, y0,   x0+1, r9, fl);
    float v10 = tapP(s, y0+1, x0,   r9, fl);
    float v11 = tapP(s, y0+1, x0+1, r9, fl);
    float top = v00*(1.0f-wx) + v01*wx;
    float bot = v10*(1.0f-wx) + v11*wx;
    out[c] = top*(1.0f-wy) + bot*wy;
  }
}

__device__ inline void rotTap(const float* __restrict__ base, int ty, int tx,
                              bool r9, bool fl, bool tr, float t, float o[3]){
  if ((unsigned)tx < 512u && (unsigned)ty < 512u){
    stage1RGB(base, ty, tx, r9, fl, tr, t, o);
  } else {
    o[0] = o[1] = o[2] = 0.0f;
  }
}

// branchless (cndmask) HSV conversions — selection among identically-computed
// candidates, bit-exact vs. the if/else versions.
__device__ inline void rgb2hsv(float r, float g, float b, float& h, float& s, float& v){
  float maxc = fmaxf(fmaxf(r, g), b);
  float minc = fminf(fminf(r, g), b);
  float cr = maxc - minc;
  s = cr / ((maxc == 0.0f) ? 1.0f : maxc);
  float crd = (cr == 0.0f) ? 1.0f : cr;
  float rc = (maxc - r) / crd;
  float gc = (maxc - g) / crd;
  float bc = (maxc - b) / crd;
  float hh = (maxc == r) ? (bc - gc) : ((maxc == g) ? (2.0f + rc - bc) : (4.0f + gc - rc));
  float hd = hh / 6.0f;
  hd = hd - floorf(hd);
  h = (cr == 0.0f) ? 0.0f : hd;
  v = maxc;
}

__device__ inline void hsv2rgb(float h, float s, float v, float& r, float& g, float& b){
  float i = floorf(h * 6.0f);
  float f = h * 6.0f - i;
  float p = v * (1.0f - s);
  float q = v * (1.0f - f * s);
  float t = v * (1.0f - (1.0f - f) * s);
  int ii = ((int)i) % 6;
  r = (ii == 0 || ii == 5) ? v : (ii == 1) ? q : (ii == 4) ? t : p;
  g = (ii == 0) ? t : (ii <= 2) ? v : (ii == 3) ? q : p;
  b = (ii <= 1) ? p : (ii == 2) ? t : (ii <= 4) ? v : q;
}

// hue+brightness on a pixel already in stage-1 space
__device__ inline void applyHB(float v[3], bool hue, bool bri, const AugParams& P){
  if (hue){
    float r = clip01(v[0]), g = clip01(v[1]), bb = clip01(v[2]);
    float h, s, val;
    rgb2hsv(r, g, bb, h, s, val);
    h = h + P.hShift;
    h = h - floorf(h);
    hsv2rgb(h, s, val, v[0], v[1], v[2]);
  }
  if (bri){
    #pragma unroll
    for (int c = 0; c < 3; ++c) v[c] = clip01(v[c] * P.bri);
  }
}

// stage-2: perm+translate+rotate+hue+brightness, straight from input
__device__ inline void stage2RGB(const float* __restrict__ base, int yy, int xx,
                                 const AugParams& P, int b, float v[3]){
  bool fl  = (P.mFlip  >> b) & 1u;
  bool r9  = (P.mRot90 >> b) & 1u;
  bool tr  = (P.mTrans >> b) & 1u;
  bool rot = (P.mRot   >> b) & 1u;
  if (rot){
    float dx = (float)xx - 255.5f;
    float dy = (float)yy - 255.5f;
    float sx = (P.rotC*dx + P.rotS*dy) + 255.5f;
    float sy = (-P.rotS*dx + P.rotC*dy) + 255.5f;
    float x0f = floorf(sx), y0f = floorf(sy);
    float wx = sx - x0f, wy = sy - y0f;
    int x0 = (int)x0f, y0 = (int)y0f;
    float q00[3], q01[3], q10[3], q11[3];
    rotTap(base, y0,   x0,   r9, fl, tr, P.t, q00);
    rotTap(base, y0,   x0+1, r9, fl, tr, P.t, q01);
    rotTap(base, y0+1, x0,   r9, fl, tr, P.t, q10);
    rotTap(base, y0+1, x0+1, r9, fl, tr, P.t, q11);
    #pragma unroll
    for (int c = 0; c < 3; ++c){
      float top = q00[c]*(1.0f-wx) + q01[c]*wx;
      float bot = q10[c]*(1.0f-wx) + q11[c]*wx;
      v[c] = top*(1.0f-wy) + bot*wy;
    }
  } else {
    stage1RGB(base, yy, xx, r9, fl, tr, P.t, v);
  }
  applyHB(v, (P.mHue >> b) & 1u, (P.mBri >> b) & 1u, P);
}

// stage-2 reading materialized stage-1 buffer: rot gather is row-local.
__device__ inline float s1at(const float* __restrict__ s, int y, int x){
  return ((unsigned)x < 512u && (unsigned)y < 512u) ? s[y*512 + x] : 0.0f;
}

__device__ inline void stage2S1(const float* __restrict__ s1b, int yy, int xx,
                                const AugParams& P, int b, float v[3]){
  bool rot = (P.mRot >> b) & 1u;
  bool hue = (P.mHue >> b) & 1u;
  bool bri = (P.mBri >> b) & 1u;
  if (rot){
    float dx = (float)xx - 255.5f;
    float dy = (float)yy - 255.5f;
    float sx = (P.rotC*dx + P.rotS*dy) + 255.5f;
    float sy = (-P.rotS*dx + P.rotC*dy) + 255.5f;
    float x0f = floorf(sx), y0f = floorf(sy);
    float wx = sx - x0f, wy = sy - y0f;
    int x0 = (int)x0f, y0 = (int)y0f;
    #pragma unroll
    for (int c = 0; c < 3; ++c){
      const float* s = s1b + c*HWSZ;
      float v00 = s1at(s, y0,   x0);
      float v01 = s1at(s, y0,   x0+1);
      float v10 = s1at(s, y0+1, x0);
      float v11 = s1at(s, y0+1, x0+1);
      float top = v00*(1.0f-wx) + v01*wx;
      float bot = v10*(1.0f-wx) + v11*wx;
      v[c] = top*(1.0f-wy) + bot*wy;
    }
  } else {
    #pragma unroll
    for (int c = 0; c < 3; ++c) v[c] = s1b[c*HWSZ + yy*512 + xx];
  }
  applyHB(v, hue, bri, P);
}

__device__ inline void procCS(float v[3], bool con, float cmul, float cadd, bool sat, float smul){
  if (con){
    #pragma unroll
    for (int c = 0; c < 3; ++c) v[c] = clip01(cmul * v[c] + cadd);
  }
  if (sat){
    float g = 0.2989f*v[0] + 0.587f*v[1] + 0.114f*v[2];
    float gadd = (1.0f - smul) * g;
    #pragma unroll
    for (int c = 0; c < 3; ++c) v[c] = clip01(smul * v[c] + gadd);
  }
}

// skipMat: batches where stage-1 is a coalesced pointwise map (no r9, no tr) —
// no S1 materialization needed; kFinalM reads the input directly.
__device__ inline bool skipMat(const AugParams& P, int b){
  bool r9  = (P.mRot90 >> b) & 1u;
  bool tr  = (P.mTrans >> b) & 1u;
  bool rot = (P.mRot   >> b) & 1u;
  return !r9 && !tr && !rot;
}

// ---------------- kernels ----------------

// ===== FAST PATH =====

// K1: fused stage-1 image (z<32) + mask stage (z>=32).
// All store paths use float4 (4 consecutive-x px per thread after the barrier).
__global__ __launch_bounds__(256) void kStage1M(const float* __restrict__ img,
                                                const float* __restrict__ msk,
                                                float* __restrict__ S1,
                                                float* __restrict__ M1,
                                                float* __restrict__ outMsk,
                                                float* __restrict__ meanAcc, AugParams P){
  __shared__ float ptile[3][33][33];
  __shared__ float wsum[4];
  int zz = blockIdx.z;
  int tx = threadIdx.x, ty = threadIdx.y;
  int tid = ty*32 + tx;
  int X0 = blockIdx.x*32, Y0 = blockIdx.y*32;
  int rowq = tid >> 3, q4 = (tid & 7)*4;   // row 0..31, x-quad base

  if (zz >= BB){
    // ---------- mask stage ----------
    int b = zz - BB;
    bool fl  = (P.mFlip  >> b) & 1u;
    bool r9  = (P.mRot90 >> b) & 1u;
    bool rot = (P.mRot   >> b) & 1u;
    const float* src = msk + (size_t)b*HWSZ;
    float* dst = (rot ? M1 : outMsk) + (size_t)b*HWSZ;
    if (!r9){
      int y = Y0 + rowq, x4 = X0 + q4;
      float4 u;
      if (!fl){
        u = *(const float4*)(src + y*512 + x4);
      } else {
        float4 w = *(const float4*)(src + y*512 + (508 - x4));
        u = make_float4(w.w, w.z, w.y, w.x);
      }
      *(float4*)(dst + y*512 + x4) = u;
    } else {
      float (*mtile)[33] = reinterpret_cast<float(*)[33]>(&ptile[0][0][0]);
      for (int idx = tid; idx < 32*32; idx += 256){
        int r = idx >> 5, q = idx & 31;
        int xx = X0 + r;                  // output col == src row
        int yy = Y0 + q;                  // output row -> src col
        int col = fl ? yy : (511 - yy);
        mtile[q][r] = src[xx*512 + col];
      }
      __syncthreads();
      int y = Y0 + rowq;
      float4 u = make_float4(mtile[rowq][q4], mtile[rowq][q4+1],
                             mtile[rowq][q4+2], mtile[rowq][q4+3]);
      *(float4*)(dst + y*512 + X0 + q4) = u;
    }
    return;
  }

  // ---------- image ----------
  int b = zz;
  bool fl  = (P.mFlip  >> b) & 1u;
  bool r9  = (P.mRot90 >> b) & 1u;
  bool tr  = (P.mTrans >> b) & 1u;
  bool rot = (P.mRot   >> b) & 1u;
  bool con = (P.mCon   >> b) & 1u;
  bool hue = (P.mHue   >> b) & 1u;
  bool bri = (P.mBri   >> b) & 1u;
  const float* base = img + (size_t)b*CHW;
  float t = P.t;
  float gsum = 0.0f;

  if (!r9 && !tr && !rot){
    // skipMat: no materialization. Mean only (flip is a pixel permutation —
    // the sum is flip-invariant, so read unflipped, fully coalesced).
    if (!con) return;
    int y = Y0 + rowq, x4 = X0 + q4;
    float4 rv = *(const float4*)(base + y*512 + x4);
    float4 gv = *(const float4*)(base + HWSZ + y*512 + x4);
    float4 bv = *(const float4*)(base + 2*HWSZ + y*512 + x4);
    float R[4] = {rv.x, rv.y, rv.z, rv.w};
    float G[4] = {gv.x, gv.y, gv.z, gv.w};
    float B[4] = {bv.x, bv.y, bv.z, bv.w};
    #pragma unroll
    for (int e = 0; e < 4; ++e){
      float w[3] = {(R[e]+1.0f)*0.5f, (G[e]+1.0f)*0.5f, (B[e]+1.0f)*0.5f};
      applyHB(w, hue, bri, P);
      gsum += 0.2989f*w[0] + 0.587f*w[1] + 0.114f*w[2];
    }
    #pragma unroll
    for (int off = 32; off > 0; off >>= 1) gsum += __shfl_down(gsum, off);
    int wid = tid >> 6, lid = tid & 63;
    if (lid == 0) wsum[wid] = gsum;
    __syncthreads();
    if (tid == 0) atomicAdd(&meanAcc[b], wsum[0] + wsum[1] + wsum[2] + wsum[3]);
    return;
  }

  // materialize S1 (+ fused mean for con && !rot)
  bool accM = con && !rot;           // block-uniform
  float* dstb = S1 + (size_t)b*CHW;

  if (!r9 && !tr){
    // (rot batches with plain/flip perm) float4 permuted copy
    int y = Y0 + rowq, x4 = X0 + q4;
    #pragma unroll
    for (int c = 0; c < 3; ++c){
      float4 u;
      if (!fl){
        u = *(const float4*)(base + c*HWSZ + y*512 + x4);
      } else {
        float4 w = *(const float4*)(base + c*HWSZ + y*512 + (508 - x4));
        u = make_float4(w.w, w.z, w.y, w.x);
      }
      u.x = (u.x + 1.0f)*0.5f; u.y = (u.y + 1.0f)*0.5f;
      u.z = (u.z + 1.0f)*0.5f; u.w = (u.w + 1.0f)*0.5f;
      *(float4*)(dstb + c*HWSZ + y*512 + x4) = u;
    }
  } else if (!r9){
    // translate-only (identical per-px arithmetic to stage1RGB), float4 stores
    int y = Y0 + rowq;
    float o[3][4];
    #pragma unroll
    for (int e = 0; e < 4; ++e){
      int x = X0 + q4 + e;
      float v[3];
      stage1RGB(base, y, x, false, fl, true, t, v);
      o[0][e] = v[0]; o[1][e] = v[1]; o[2][e] = v[2];
      if (accM){
        float w[3] = {v[0], v[1], v[2]};
        applyHB(w, hue, bri, P);
        gsum += 0.2989f*w[0] + 0.587f*w[1] + 0.114f*w[2];
      }
    }
    #pragma unroll
    for (int c = 0; c < 3; ++c){
      float4 u = make_float4(o[c][0], o[c][1], o[c][2], o[c][3]);
      *(float4*)(dstb + (size_t)c*HWSZ + (size_t)y*512 + X0 + q4) = u;
    }
  } else {
    // r9 (optionally + tr): staged LDS transpose, all channels, single barrier,
    // float4 stores (4 consecutive-x px per thread)
    #pragma unroll
    for (int c = 0; c < 3; ++c){
      const float* src = base + c*HWSZ;
      for (int idx = tid; idx < 33*33; idx += 256){
        int r = idx / 33, q = idx - r*33;
        int xx = X0 - 1 + r;      // output col == src row
        int yy = Y0 - 1 + q;      // output row -> src col
        float val = 0.0f;
        if ((unsigned)yy < 512u && (unsigned)xx < 512u){
          int col = fl ? yy : (511 - yy);
          val = (src[xx*512 + col] + 1.0f) * 0.5f;
        }
        ptile[c][q][r] = val;     // transpose store
      }
    }
    __syncthreads();
    int y = Y0 + rowq;
    float o[3][4];
    if (tr){
      float sy = (((float)y - 255.5f) - t) + 255.5f;
      float y0f = floorf(sy);
      float wy = sy - y0f;
      int ly0 = (int)y0f - (Y0 - 1);
      #pragma unroll
      for (int e = 0; e < 4; ++e){
        int x = X0 + q4 + e;
        float sx = (((float)x - 255.5f) - t) + 255.5f;
        float x0f = floorf(sx);
        float wx = sx - x0f;
        int lx0 = (int)x0f - (X0 - 1);
        float v[3];
        #pragma unroll
        for (int c = 0; c < 3; ++c){
          float v00 = ptile[c][ly0][lx0],   v01 = ptile[c][ly0][lx0+1];
          float v10 = ptile[c][ly0+1][lx0], v11 = ptile[c][ly0+1][lx0+1];
          float top = v00*(1.0f-wx) + v01*wx;
          float bot = v10*(1.0f-wx) + v11*wx;
          v[c] = top*(1.0f-wy) + bot*wy;
          o[c][e] = v[c];
        }
        if (accM){
          float w[3] = {v[0], v[1], v[2]};
          applyHB(w, hue, bri, P);
          gsum += 0.2989f*w[0] + 0.587f*w[1] + 0.114f*w[2];
        }
      }
    } else {
      #pragma unroll
      for (int e = 0; e < 4; ++e){
        float v[3];
        #pragma unroll
        for (int c = 0; c < 3; ++c){
          v[c] = ptile[c][rowq+1][q4+e+1];
          o[c][e] = v[c];
        }
        if (accM){
          float w[3] = {v[0], v[1], v[2]};
          applyHB(w, hue, bri, P);
          gsum += 0.2989f*w[0] + 0.587f*w[1] + 0.114f*w[2];
        }
      }
    }
    #pragma unroll
    for (int c = 0; c < 3; ++c){
      float4 u = make_float4(o[c][0], o[c][1], o[c][2], o[c][3]);
      *(float4*)(dstb + (size_t)c*HWSZ + (size_t)y*512 + X0 + q4) = u;
    }
  }

  if (accM){
    #pragma unroll
    for (int off = 32; off > 0; off >>= 1) gsum += __shfl_down(gsum, off);
    int wid = tid >> 6, lid = tid & 63;
    if (lid == 0) wsum[wid] = gsum;
    __syncthreads();
    if (tid == 0) atomicAdd(&meanAcc[b], wsum[0] + wsum[1] + wsum[2] + wsum[3]);
  }
}

// K2: contrast mean for rot && con batches (from S1, row-local gather).
// Dense z: blockIdx.z indexes P.meanList (host packs active batches).
__global__ __launch_bounds__(256) void kMean2(const float* __restrict__ S1,
                                              float* __restrict__ meanAcc, AugParams P){
  int b = (int)P.meanList[blockIdx.z];
  int tid = threadIdx.x;                 // 256 threads, 1-D block
  const float* base = S1 + (size_t)b*CHW;
  int pbase = blockIdx.x * 1024;         // 256 blocks cover 262144 px
  float lsum = 0.0f;

  #pragma unroll
  for (int j = 0; j < 4; ++j){
    int px = pbase + j*256 + tid;
    int y = px >> 9, x = px & 511;
    float v[3];
    stage2S1(base, y, x, P, b, v);
    lsum += 0.2989f*v[0] + 0.587f*v[1] + 0.114f*v[2];
  }

  #pragma unroll
  for (int off = 32; off > 0; off >>= 1) lsum += __shfl_down(lsum, off);
  __shared__ float wsum[4];
  int wid = tid >> 6, lid = tid & 63;
  if (lid == 0) wsum[wid] = lsum;
  __syncthreads();
  if (tid == 0) atomicAdd(&meanAcc[b], wsum[0] + wsum[1] + wsum[2] + wsum[3]);
}

// K3: fused final image (z<32) + mask nearest-rotation (z>=32).
// skipMat batches read the input directly (coalesced pointwise); all others read S1.
__global__ __launch_bounds__(256) void kFinalM(const float* __restrict__ img,
                                               const float* __restrict__ S1,
                                               const float* __restrict__ M1,
                                               const float* __restrict__ meanAcc,
                                               float* __restrict__ out,
                                               float* __restrict__ outMsk, AugParams P){
  __shared__ float s2[34][34][3];
  int zz = blockIdx.z;
  int tx = threadIdx.x, ty = threadIdx.y;
  int tid = ty*32 + tx;
  int bx = blockIdx.x, by = blockIdx.y;

  if (zz >= BB){
    // ---------- mask nearest-rot gather (row-local reads from permuted M1) ----------
    int b = zz - BB;
    if (!((P.mRot >> b) & 1u)) return;
    const float* src = M1 + (size_t)b*HWSZ;
    float* dst = outMsk + (size_t)b*HWSZ;
    int X0 = bx*32, Y0 = by*32;
    #pragma unroll
    for (int k = 0; k < 4; ++k){
      int x = X0 + tx, y = Y0 + ty + 8*k;
      float dx = __fsub_rn((float)x, 255.5f);
      float dy = __fsub_rn((float)y, 255.5f);
      float sx = __fadd_rn(__fadd_rn(__fmul_rn(P.rotC, dx), __fmul_rn(P.rotS, dy)), 255.5f);
      float sy = __fadd_rn(__fadd_rn(__fmul_rn(-P.rotS, dx), __fmul_rn(P.rotC, dy)), 255.5f);
      float xi = rintf(sx), yi = rintf(sy);
      bool valid = (xi >= 0.0f) && (xi < 512.0f) && (yi >= 0.0f) && (yi < 512.0f);
      int xc = (int)fminf(fmaxf(xi, 0.0f), 511.0f);
      int yc = (int)fminf(fmaxf(yi, 0.0f), 511.0f);
      float v = valid ? src[yc*512 + xc] : 0.0f;
      dst[y*512 + x] = v;
    }
    return;
  }

  // ---------- image final ----------
  int b = zz;
  const float W1 = 1.0f/13.0f, W5 = 5.0f/13.0f;
  bool fl  = (P.mFlip  >> b) & 1u;
  bool rot = (P.mRot   >> b) & 1u;
  bool hue = (P.mHue   >> b) & 1u;
  bool bri = (P.mBri   >> b) & 1u;
  bool con = (P.mCon   >> b) & 1u;
  bool sat = (P.mSat   >> b) & 1u;
  bool shg = (P.mSharp >> b) & 1u;
  bool noi = (P.mNoise >> b) & 1u;
  bool skip = skipMat(P, b);
  float mean = meanAcc[b] * (1.0f/262144.0f);
  float cadd = (1.0f - P.con) * mean;
  const float* s1b = S1 + (size_t)b*CHW;
  const float* imb = img + (size_t)b*CHW;

  if (!shg && (skip || !rot)){
    // pointwise float4 path (skip: from input with flip; else: from S1, already permuted)
    int row = tid >> 3, q = tid & 7;
    int y = by*32 + row; int x4 = bx*32 + q*4;
    float4 rv, gv, bv;
    if (skip){
      if (!fl){
        rv = *(const float4*)(imb + y*512 + x4);
        gv = *(const float4*)(imb + HWSZ + y*512 + x4);
        bv = *(const float4*)(imb + 2*HWSZ + y*512 + x4);
      } else {
        float4 rw = *(const float4*)(imb + y*512 + (508 - x4));
        float4 gw = *(const float4*)(imb + HWSZ + y*512 + (508 - x4));
        float4 bw = *(const float4*)(imb + 2*HWSZ + y*512 + (508 - x4));
        rv = make_float4(rw.w, rw.z, rw.y, rw.x);
        gv = make_float4(gw.w, gw.z, gw.y, gw.x);
        bv = make_float4(bw.w, bw.z, bw.y, bw.x);
      }
      rv.x = (rv.x+1.0f)*0.5f; rv.y = (rv.y+1.0f)*0.5f; rv.z = (rv.z+1.0f)*0.5f; rv.w = (rv.w+1.0f)*0.5f;
      gv.x = (gv.x+1.0f)*0.5f; gv.y = (gv.y+1.0f)*0.5f; gv.z = (gv.z+1.0f)*0.5f; gv.w = (gv.w+1.0f)*0.5f;
      bv.x = (bv.x+1.0f)*0.5f; bv.y = (bv.y+1.0f)*0.5f; bv.z = (bv.z+1.0f)*0.5f; bv.w = (bv.w+1.0f)*0.5f;
    } else {
      rv = *(const float4*)(s1b + y*512 + x4);
      gv = *(const float4*)(s1b + HWSZ + y*512 + x4);
      bv = *(const float4*)(s1b + 2*HWSZ + y*512 + x4);
    }
    float R[4] = {rv.x, rv.y, rv.z, rv.w};
    float G[4] = {gv.x, gv.y, gv.z, gv.w};
    float B[4] = {bv.x, bv.y, bv.z, bv.w};
    float O[3][4];
    #pragma unroll
    for (int e = 0; e < 4; ++e){
      float v[3] = {R[e], G[e], B[e]};
      applyHB(v, hue, bri, P);
      procCS(v, con, P.con, cadd, sat, P.sat);
      if (noi){
        #pragma unroll
        for (int c = 0; c < 3; ++c){
          uint32_t idx = (uint32_t)(b*CHW + c*HWSZ + y*512 + x4 + e);
          uint32_t o0, o1;
          tf2x32(P.nk0, P.nk1, 0u, idx, o0, o1);
          v[c] += normal_from_bits(o0 ^ o1) * 0.1f;
        }
      }
      #pragma unroll
      for (int c = 0; c < 3; ++c) O[c][e] = (v[c] - 0.5f) * 2.0f;
    }
    #pragma unroll
    for (int c = 0; c < 3; ++c){
      float4 w = make_float4(O[c][0], O[c][1], O[c][2], O[c][3]);
      *(float4*)(out + (size_t)b*CHW + (size_t)c*HWSZ + (size_t)y*512 + x4) = w;
    }
    return;   // block-uniform
  }

  if (!shg){
    // rot, no sharpness: scalar rot gather from S1, no LDS
    #pragma unroll
    for (int k = 0; k < 4; ++k){
      int x = bx*32 + tx, y = by*32 + ty + 8*k;
      float res[3];
      stage2S1(s1b, y, x, P, b, res);
      procCS(res, con, P.con, cadd, sat, P.sat);
      if (noi){
        #pragma unroll
        for (int c = 0; c < 3; ++c){
          uint32_t idx = (uint32_t)(b*CHW + c*HWSZ + y*512 + x);
          uint32_t o0, o1;
          tf2x32(P.nk0, P.nk1, 0u, idx, o0, o1);
          res[c] += normal_from_bits(o0 ^ o1) * 0.1f;
        }
      }
      #pragma unroll
      for (int c = 0; c < 3; ++c){
        out[(size_t)b*CHW + (size_t)c*HWSZ + (size_t)y*512 + x] = (res[c] - 0.5f) * 2.0f;
      }
    }
    return;   // block-uniform
  }

  // sharpness: stage-2 + con/sat -> LDS halo tile (34x34), sharpen, noise, write.
  // skip batches source the halo from the input (coalesced pointwise); others from S1.
  for (int cell = tid; cell < 34*34; cell += 256){
    int r = cell / 34, cc = cell - r*34;
    int gy = by*32 + r - 1, gx = bx*32 + cc - 1;
    float v[3] = {0.0f, 0.0f, 0.0f};
    if ((unsigned)gx < 512u && (unsigned)gy < 512u){
      if (skip) stage2RGB(imb, gy, gx, P, b, v);
      else      stage2S1(s1b, gy, gx, P, b, v);
      procCS(v, con, P.con, cadd, sat, P.sat);
    }
    s2[r][cc][0] = v[0]; s2[r][cc][1] = v[1]; s2[r][cc][2] = v[2];
  }
  __syncthreads();

  for (int k = 0; k < 4; ++k){
    int yy = ty + 8*k;
    int x = bx*32 + tx, y = by*32 + yy;
    bool interior = (x >= 1) && (x <= 510) && (y >= 1) && (y <= 510);
    float res[3];
    float c0[3] = { s2[yy+1][tx+1][0], s2[yy+1][tx+1][1], s2[yy+1][tx+1][2] };
    if (interior){
      float nsum[3] = {0.0f, 0.0f, 0.0f};
      #pragma unroll
      for (int dy = 0; dy < 3; ++dy){
        #pragma unroll
        for (int dxx = 0; dxx < 3; ++dxx){
          if (dxx == 1 && dy == 1) continue;
          #pragma unroll
          for (int c = 0; c < 3; ++c) nsum[c] += s2[yy+dy][tx+dxx][c];
        }
      }
      #pragma unroll
      for (int c = 0; c < 3; ++c){
        float bl = clip01(nsum[c]*W1 + c0[c]*W5);
        res[c] = clip01(P.shp * c0[c] + (1.0f - P.shp) * bl);
      }
    } else {
      res[0] = c0[0]; res[1] = c0[1]; res[2] = c0[2];
    }

    if (noi){
      #pragma unroll
      for (int c = 0; c < 3; ++c){
        uint32_t idx = (uint32_t)(b*CHW + c*HWSZ + y*512 + x);
        uint32_t o0, o1;
        tf2x32(P.nk0, P.nk1, 0u, idx, o0, o1);
        res[c] += normal_from_bits(o0 ^ o1) * 0.1f;
      }
    }
    #pragma unroll
    for (int c = 0; c < 3; ++c){
      out[(size_t)b*CHW + (size_t)c*HWSZ + (size_t)y*512 + x] = (res[c] - 0.5f) * 2.0f;
    }
  }
}

// ===== FALLBACK PATH (previous proven kernels) =====

__global__ __launch_bounds__(256) void kMask(const float* __restrict__ msk,
                                             float* __restrict__ out, AugParams P){
  int x = blockIdx.x*blockDim.x + threadIdx.x;
  int y = blockIdx.y*blockDim.y + threadIdx.y;
  int b = blockIdx.z;
  bool fl  = (P.mFlip  >> b) & 1u;
  bool r9  = (P.mRot90 >> b) & 1u;
  bool rot = (P.mRot   >> b) & 1u;
  float v;
  if (rot){
    float dx = __fsub_rn((float)x, 255.5f);
    float dy = __fsub_rn((float)y, 255.5f);
    float sx = __fadd_rn(__fadd_rn(__fmul_rn(P.rotC, dx), __fmul_rn(P.rotS, dy)), 255.5f);
    float sy = __fadd_rn(__fadd_rn(__fmul_rn(-P.rotS, dx), __fmul_rn(P.rotC, dy)), 255.5f);
    float xi = rintf(sx), yi = rintf(sy);
    bool valid = (xi >= 0.0f) && (xi < 512.0f) && (yi >= 0.0f) && (yi < 512.0f);
    int xc = (int)fminf(fmaxf(xi, 0.0f), 511.0f);
    int yc = (int)fminf(fmaxf(yi, 0.0f), 511.0f);
    int py, px; permIdx(yc, xc, r9, fl, py, px);
    v = valid ? msk[(size_t)b*HWSZ + py*512 + px] : 0.0f;
  } else {
    int py, px; permIdx(y, x, r9, fl, py, px);
    v = msk[(size_t)b*HWSZ + py*512 + px];
  }
  out[(size_t)b*HWSZ + y*512 + x] = v;
}

__global__ __launch_bounds__(256) void kMean(const float* __restrict__ img,
                                             float* __restrict__ meanAcc, AugParams P){
  int b = blockIdx.z;
  if (!((P.mCon >> b) & 1u)) return;
  int x = blockIdx.x*blockDim.x + threadIdx.x;
  int y = blockIdx.y*blockDim.y + threadIdx.y;
  float v[3];
  stage2RGB(img + (size_t)b*CHW, y, x, P, b, v);
  float gray = 0.2989f*v[0] + 0.587f*v[1] + 0.114f*v[2];
  __shared__ float sred[256];
  int tid = threadIdx.y*blockDim.x + threadIdx.x;
  sred[tid] = gray;
  __syncthreads();
  for (int s = 128; s > 0; s >>= 1){
    if (tid < s) sred[tid] += sred[tid + s];
    __syncthreads();
  }
  if (tid == 0) atomicAdd(&meanAcc[b], sred[0]);
}

__global__ __launch_bounds__(256) void kFinal(const float* __restrict__ img,
                                              const float* __restrict__ meanAcc,
                                              float* __restrict__ out, AugParams P){
  __shared__ float s2[10][34][3];
  int tx = threadIdx.x, ty = threadIdx.y;
  int tid = ty*32 + tx;
  int bx = blockIdx.x, by = blockIdx.y, b = blockIdx.z;
  const float W1 = 1.0f/13.0f, W5 = 5.0f/13.0f;

  bool con = (P.mCon   >> b) & 1u;
  bool sat = (P.mSat   >> b) & 1u;
  bool shg = (P.mSharp >> b) & 1u;
  bool noi = (P.mNoise >> b) & 1u;
  float mean = meanAcc[b] * (1.0f/262144.0f);
  float cadd = (1.0f - P.con) * mean;
  const float* base = img + (size_t)b*CHW;

  for (int cell = tid; cell < 340; cell += 256){
    int r = cell / 34, cc = cell % 34;
    int gy = by*8 + r - 1, gx = bx*32 + cc - 1;
    float v[3] = {0.0f, 0.0f, 0.0f};
    if ((unsigned)gx < 512u && (unsigned)gy < 512u){
      stage2RGB(base, gy, gx, P, b, v);
      procCS(v, con, P.con, cadd, sat, P.sat);
    }
    s2[r][cc][0] = v[0]; s2[r][cc][1] = v[1]; s2[r][cc][2] = v[2];
  }
  __syncthreads();

  int x = bx*32 + tx, y = by*8 + ty;
  bool interior = (x >= 1) && (x <= 510) && (y >= 1) && (y <= 510);
  float res[3];
  float c0[3] = { s2[ty+1][tx+1][0], s2[ty+1][tx+1][1], s2[ty+1][tx+1][2] };
  if (shg && interior){
    float nsum[3] = {0.0f, 0.0f, 0.0f};
    #pragma unroll
    for (int dy = 0; dy < 3; ++dy){
      #pragma unroll
      for (int dxx = 0; dxx < 3; ++dxx){
        if (dxx == 1 && dy == 1) continue;
        #pragma unroll
        for (int c = 0; c < 3; ++c) nsum[c] += s2[ty+dy][tx+dxx][c];
      }
    }
    #pragma unroll
    for (int c = 0; c < 3; ++c){
      float bl = clip01(nsum[c]*W1 + c0[c]*W5);
      res[c] = clip01(P.shp * c0[c] + (1.0f - P.shp) * bl);
    }
  } else {
    res[0] = c0[0]; res[1] = c0[1]; res[2] = c0[2];
  }

  if (noi){
    #pragma unroll
    for (int c = 0; c < 3; ++c){
      uint32_t idx = (uint32_t)(b*CHW + c*HWSZ + y*512 + x);
      uint32_t o0, o1;
      tf2x32(P.nk0, P.nk1, 0u, idx, o0, o1);
      res[c] += normal_from_bits(o0 ^ o1) * 0.1f;
    }
  }
  #pragma unroll
  for (int c = 0; c < 3; ++c){
    out[(size_t)b*CHW + (size_t)c*HWSZ + y*512 + x] = (res[c] - 0.5f) * 2.0f;
  }
}

// ---------------- launch ----------------
extern "C" void kernel_launch(void* const* d_in, const int* in_sizes, int n_in,
                              void* d_out, int out_size, void* d_ws, size_t ws_size,
                              hipStream_t stream) {
  (void)in_sizes; (void)n_in; (void)out_size;
  const float* images = (const float*)d_in[0];
  const float* masks  = (const float*)d_in[1];
  float* out_img = (float*)d_out;
  float* out_msk = out_img + (size_t)NIMG;
  float* meanAcc = (float*)d_ws;   // 32 floats (first 256 B of ws)

  Key root; root.a = 0u; root.b = 42u;
  Key ks[18];
  for (uint32_t j = 0; j < 18; ++j) ks[j] = foldSplit(root, j);

  AugParams P;
  P.mFlip  = gate_mask(ks[0]);
  P.mRot90 = gate_mask(ks[1]);
  P.mTrans = gate_mask(ks[2]);
  P.t      = unif_scalar(ks[3]) * 0.125f;
  P.mRot   = gate_mask(ks[4]);
  float r  = unif_scalar(ks[5]) * 10.0f;
  P.mHue   = gate_mask(ks[6]);
  P.hShift = (unif_scalar(ks[7]) - 0.5f) * 0.95f;
  P.mBri   = gate_mask(ks[8]);
  P.bri    = fabsf(1.0f + normal_scalar(ks[9])  * 0.2f);
  P.mCon   = gate_mask(ks[10]);
  P.con    = fabsf(1.0f + normal_scalar(ks[11]) * 0.2f);
  P.mSat   = gate_mask(ks[12]);
  P.sat    = fabsf(1.0f + normal_scalar(ks[13]) * 0.2f);
  P.mSharp = gate_mask(ks[14]);
  P.shp    = fabsf(1.0f + normal_scalar(ks[15]) * 1.0f);
  P.mNoise = gate_mask(ks[16]);
  P.nk0 = ks[17].a; P.nk1 = ks[17].b;

  // t == 0 would need a right halo in kStage1M; translation with t==0 is exact
  // identity (sx == x bit-exactly), so just clear the gate.
  if (!(P.t > 0.0f)) P.mTrans = 0u;

  float th = r * 0.017453292519943295f;   // single f32 multiply (match XLA deg2rad)
  P.rotC = (float)cos((double)th);
  P.rotS = (float)sin((double)th);

  // dense list of rot && con batches for kMean2 (gates are host-known)
  P.nMeanB = 0;
  uint32_t mrc = P.mRot & P.mCon;
  for (int b = 0; b < 32; ++b){
    if ((mrc >> b) & 1u) P.meanList[P.nMeanB++] = (uint8_t)b;
  }

  dim3 blk(32, 8, 1);
  const size_t needFull = ((size_t)NIMG + (size_t)NMSK + 64) * sizeof(float);
  const size_t needImg  = ((size_t)NIMG + 64) * sizeof(float);
  const int zFin = P.mRot ? 64 : 32;   // mask-rot half only needed if any rot batch

  hipMemsetAsync(meanAcc, 0, 32*sizeof(float), stream);

  if (ws_size >= needFull){
    float* S1 = (float*)d_ws + 64;
    float* M1 = S1 + (size_t)NIMG;
    kStage1M<<<dim3(16, 16, 64), blk, 0, stream>>>(images, masks, S1, M1, out_msk, meanAcc, P);
    if (P.nMeanB)
      kMean2<<<dim3(256, 1, P.nMeanB), dim3(256,1,1), 0, stream>>>(S1, meanAcc, P);
    kFinalM<<<dim3(16, 16, zFin), blk, 0, stream>>>(images, S1, M1, meanAcc, out_img, out_msk, P);
  } else if (ws_size >= needImg){
    float* S1 = (float*)d_ws + 64;
    kMask   <<<dim3(16, 64, 32), blk, 0, stream>>>(masks, out_msk, P);
    kStage1M<<<dim3(16, 16, 32), blk, 0, stream>>>(images, masks, S1, nullptr, out_msk, meanAcc, P);
    if (P.nMeanB)
      kMean2<<<dim3(256, 1, P.nMeanB), dim3(256,1,1), 0, stream>>>(S1, meanAcc, P);
    kFinalM<<<dim3(16, 16, 32), blk, 0, stream>>>(images, S1, nullptr, meanAcc, out_img, out_msk, P);
  } else {
    kMask <<<dim3(16, 64, 32), blk, 0, stream>>>(masks, out_msk, P);
    kMean <<<dim3(16, 64, 32), blk, 0, stream>>>(images, meanAcc, P);
    kFinal<<<dim3(16, 64, 32), blk, 0, stream>>>(images, meanAcc, out_img, P);
  }
}